// Round 10
// baseline (159.886 us; speedup 1.0000x reference)
//
#include <hip/hip_runtime.h>
#include <hip/hip_bf16.h>
#include <cstdint>

#define WPOS 251
#define NBB  30
#define NCH  512
#define RELP 501
#define NEPS 1e-5f

typedef _Float16 half2_t __attribute__((ext_vector_type(2)));
typedef _Float16 half8_t __attribute__((ext_vector_type(8)));
typedef float f32x16_t __attribute__((ext_vector_type(16)));

#if defined(__has_builtin)
#if __has_builtin(__builtin_amdgcn_fdot2)
#define FDOT2(a, b, c) __builtin_amdgcn_fdot2((a), (b), (c), false)
#endif
#endif
#ifndef FDOT2
#define FDOT2(a, b, c) ((float)(a)[0] * (float)(b)[0] + (float)(a)[1] * (float)(b)[1] + (c))
#endif

// ---------------- workspace layout (in float slots) ----------------
static constexpr size_t SZ_Z     = (size_t)NBB * NCH * WPOS;
static constexpr size_t OFF_Z    = 0;
static constexpr size_t OFF_VH   = OFF_Z + SZ_Z;                   // uint[bbh][128][32] half2 v pairs
static constexpr size_t SZ_VH    = (size_t)NBB * 8 * 128 * 32;
static constexpr size_t OFF_RETC = OFF_VH + SZ_VH;                 // uint[501][16]: qe|keR fp16 pairs
static constexpr size_t OFF_VETP = OFF_RETC + (size_t)RELP * 16;   // uint[256][32] half2 p-pairs
static constexpr size_t OFF_P1Q  = OFF_VETP + (size_t)256 * 32;    // [16][502]
static constexpr size_t OFF_P1K  = OFF_P1Q + (size_t)16 * 502;
static constexpr size_t OFF_P2Q  = OFF_P1K + (size_t)16 * 502;     // [256][502]
static constexpr size_t OFF_P2K  = OFF_P2Q + (size_t)256 * 502;
static constexpr size_t OFF_LPP  = OFF_P2K + (size_t)256 * 502;    // [960][548] partials
static constexpr size_t OFF_ACC  = OFF_LPP + (size_t)960 * 548;    // csum[512] csum2[512] lacc[48]

static __device__ __forceinline__ unsigned packh2(float a, float b) {
  half2_t t;
  t[0] = (_Float16)a;
  t[1] = (_Float16)b;
  return __builtin_bit_cast(unsigned, t);
}
static __device__ __forceinline__ half2_t ash2(unsigned u) {
  return __builtin_bit_cast(half2_t, u);
}

// ---------------- K0: rel prep (64 blocks) + prefix scans (544 blocks) ----------------
__global__ __launch_bounds__(256) void k_pre(
    const float* __restrict__ rel, unsigned* __restrict__ retc, unsigned* __restrict__ vetp,
    float* __restrict__ p1q, float* __restrict__ p1k,
    float* __restrict__ p2q, float* __restrict__ p2k) {
  int blk = blockIdx.x;
  if (blk < 64) {
    int idx = blk * 256 + threadIdx.x;
    if (idx < RELP * 16) {
      int p = idx >> 4, j = idx & 15;
      float lo, hi;
      if (j < 8) {
        lo = rel[(size_t)(2 * j) * RELP + p];
        hi = rel[(size_t)(2 * j + 1) * RELP + p];
      } else {
        int jj = j - 8;
        lo = rel[(size_t)(16 + 2 * jj) * RELP + (500 - p)];
        hi = rel[(size_t)(17 + 2 * jj) * RELP + (500 - p)];
      }
      retc[(size_t)p * 16 + j] = packh2(lo, hi);
    } else if (idx < RELP * 16 + 256 * 32) {
      int i2 = idx - RELP * 16;
      int t = i2 >> 5, ch = i2 & 31;
      float lo = (2 * t <= 500) ? rel[(size_t)(32 + ch) * RELP + 2 * t] : 0.f;
      float hi = (2 * t + 1 <= 500) ? rel[(size_t)(32 + ch) * RELP + 2 * t + 1] : 0.f;
      vetp[(size_t)t * 32 + ch] = packh2(lo, hi);
    }
    return;
  }
  int task = blk - 64;   // 0..543
  const float* ra;
  const float* rb = nullptr;
  float* outp;
  if (task < 16)        { ra = rel + (size_t)task * RELP; outp = p1q + (size_t)task * 502; }
  else if (task < 32)   { ra = rel + (size_t)task * RELP; outp = p1k + (size_t)(task - 16) * 502; }
  else if (task < 288)  { int pr = task - 32;
                          ra = rel + (size_t)(pr >> 4) * RELP;
                          rb = rel + (size_t)(pr & 15) * RELP;
                          outp = p2q + (size_t)pr * 502; }
  else                  { int pr = task - 288;
                          ra = rel + (size_t)(16 + (pr >> 4)) * RELP;
                          rb = rel + (size_t)(16 + (pr & 15)) * RELP;
                          outp = p2k + (size_t)pr * 502; }
  __shared__ float buf[256];
  int t = threadIdx.x;
  int i0 = 2 * t, i1 = 2 * t + 1;
  float a0 = (i0 < RELP) ? (rb ? ra[i0] * rb[i0] : ra[i0]) : 0.f;
  float a1 = (i1 < RELP) ? (rb ? ra[i1] * rb[i1] : ra[i1]) : 0.f;
  buf[t] = a0 + a1;
  __syncthreads();
#pragma unroll
  for (int off = 1; off < 256; off <<= 1) {
    float v = buf[t];
    float add = (t >= off) ? buf[t - off] : 0.f;
    __syncthreads();
    buf[t] = v + add;
    __syncthreads();
  }
  float ex = buf[t] - (a0 + a1);
  if (i0 <= RELP) outp[i0] = ex;
  if (i1 <= RELP) outp[i1] = ex + a0;
}

// ---------------- K1: kqv GEMM via fp16 MFMA + channel-stat partials ----------------
__global__ __launch_bounds__(256) void k_gemm(
    const float* __restrict__ x, const float* __restrict__ y,
    const float* __restrict__ wk, const float* __restrict__ wq,
    const float* __restrict__ wv, float* __restrict__ z,
    float* __restrict__ csum, float* __restrict__ csum2) {
  int l0 = blockIdx.x * 64;
  int o0 = blockIdx.y * 64;
  int bb = blockIdx.z;
  int b = bb / 15, hi = bb % 15;
  const float* src;
  const float* wmat;
  int orow0;
  if (o0 < 128)      { wmat = wk; orow0 = o0;       src = x; }
  else if (o0 < 256) { wmat = wq; orow0 = o0 - 128; src = y; }
  else               { wmat = wv; orow0 = o0 - 256; src = x; }

  __shared__ _Float16 Ah[64][68];   // [o][k]
  __shared__ _Float16 Bh[64][68];   // [k][l]

  int tid = threadIdx.x;
  int lane = tid & 63, wv4 = tid >> 6;
  int wo = wv4 >> 1, wl = wv4 & 1;
  int m = lane & 31, kh = lane >> 5;

  f32x16_t acc = {};

  int cA = tid & 63, ogA = tid >> 6;
  int lB = tid & 63, kgB = tid >> 6;
  int lglob = l0 + lB;
  bool lok = (lglob < WPOS);
  const float* xcol = src + (size_t)(((size_t)b * 256) * 15 + hi) * WPOS + lglob;

  for (int c0 = 0; c0 < 256; c0 += 64) {
#pragma unroll
    for (int i = 0; i < 16; ++i) {
      int o = ogA * 16 + i;
      Ah[o][cA] = (_Float16)wmat[(size_t)(orow0 + o) * 256 + c0 + cA];
    }
#pragma unroll
    for (int i = 0; i < 16; ++i) {
      int k = kgB * 16 + i;
      float v = lok ? xcol[(size_t)(c0 + k) * 15 * WPOS] : 0.f;
      Bh[k][lB] = (_Float16)v;
    }
    __syncthreads();
#pragma unroll
    for (int ks = 0; ks < 4; ++ks) {
      const _Float16* ap = &Ah[wo * 32 + m][ks * 16 + kh * 8];
      uint2 aLo = *(const uint2*)(ap);
      uint2 aHi = *(const uint2*)(ap + 4);
      uint4 au = {aLo.x, aLo.y, aHi.x, aHi.y};
      half8_t af = __builtin_bit_cast(half8_t, au);
      half8_t bf;
      int kb = ks * 16 + kh * 8;
      int bcol = wl * 32 + m;
#pragma unroll
      for (int e = 0; e < 8; ++e) bf[e] = Bh[kb + e][bcol];
      acc = __builtin_amdgcn_mfma_f32_32x32x16_f16(af, bf, acc, 0, 0, 0);
    }
    __syncthreads();
  }

  int n = lane & 31;
  int lout = l0 + wl * 32 + n;
  if (lout < WPOS) {
#pragma unroll
    for (int r = 0; r < 16; ++r) {
      int mrow = (r & 3) + 8 * (r >> 2) + 4 * kh;
      int o = o0 + wo * 32 + mrow;
      z[((size_t)bb * NCH + o) * WPOS + lout] = acc[r];
    }
  }

  // ---- channel partial sums (invalid cols are exactly 0 -> no masking) ----
#pragma unroll
  for (int r = 0; r < 16; ++r) {
    float s = acc[r];
    float s2 = s * s;
#pragma unroll
    for (int m2 = 1; m2 < 32; m2 <<= 1) {
      s  += __shfl_xor(s, m2, 64);
      s2 += __shfl_xor(s2, m2, 64);
    }
    if (n == 0) {
      int mrow = (r & 3) + 8 * (r >> 2) + 4 * kh;
      int o = o0 + wo * 32 + mrow;
      atomicAdd(&csum[o], s);
      atomicAdd(&csum2[o], s2);
    }
  }
}

// ---------------- helpers ----------------
__device__ __forceinline__ float block_reduce(float v, float* red, int tid) {
  red[tid] = v; __syncthreads();
  for (int s = 128; s > 0; s >>= 1) {
    if (tid < s) red[tid] += red[tid + s];
    __syncthreads();
  }
  float r = red[0]; __syncthreads();
  return r;
}

__device__ __forceinline__ void chan_affine(
    int ch, const float* gk, const float* bk, const float* gq, const float* bq,
    const float* gkq, const float* bkq, const float* csum, const float* csum2,
    float& a, float& bout) {
  float g, bi;
  if (ch < 128)      { g = gk[ch];        bi = bk[ch]; }
  else if (ch < 256) { g = gq[ch - 128];  bi = bq[ch - 128]; }
  else               { g = gkq[ch - 256]; bi = bkq[ch - 256]; }
  float n = (float)(NBB * WPOS);
  float mean = csum[ch] / n;
  float var = csum2[ch] / n - mean * mean;
  a = g / sqrtf(var + NEPS);
  bout = bi - mean * a;
}

// ---------------- K2: merged norm_vh (blocks 0..959) + lstats1 (960..1919) ----------------
__global__ __launch_bounds__(256) void k_mid(
    const float* __restrict__ z,
    const float* __restrict__ gk, const float* __restrict__ bk,
    const float* __restrict__ gq, const float* __restrict__ bq,
    const float* __restrict__ gkq, const float* __restrict__ bkq,
    const float* __restrict__ csum, const float* __restrict__ csum2,
    unsigned* __restrict__ vh,
    const float* __restrict__ p1q, const float* __restrict__ p1k,
    const float* __restrict__ p2q, const float* __restrict__ p2k,
    float* __restrict__ lpp) {
  int blk = blockIdx.x;
  bool isV = (blk < 960);
  int sblk = isV ? blk : blk - 960;
  int bbh = sblk % 240, sub = sblk / 240;
  int bb = bbh >> 3, h = bbh & 7;
  int tid = threadIdx.x;

  __shared__ __align__(16) float pool[16 * 68 * 2];   // T[32][65] or qs/ks[16][68]
  __shared__ float red[256];
  __shared__ float caL[32], cbL[32];

  if (tid < 32) {
    int ch = h * 64 + (isV ? 32 + tid : tid);
    chan_affine(ch, gk, bk, gq, bq, gkq, bkq, csum, csum2, caL[tid], cbL[tid]);
  }
  __syncthreads();

  if (isV) {
    float (*T)[65] = (float(*)[65])pool;
    int l0 = sub * 64;
    const float* zv = z + ((size_t)bb * NCH + h * 64 + 32) * WPOS;
    for (int i = tid; i < 32 * 64; i += 256) {
      int ch = i >> 6, l = i & 63;
      int gl = l0 + l;
      T[ch][l] = (gl < WPOS) ? (caL[ch] * zv[(size_t)ch * WPOS + gl] + cbL[ch]) : 0.f;
    }
    __syncthreads();
    int p0 = l0 >> 1;
    for (int i = tid; i < 32 * 32; i += 256) {
      int pl = i >> 5, ch = i & 31;
      int gp = p0 + pl;
      if (gp < 128)
        vh[((size_t)bbh * 128 + gp) * 32 + ch] = packh2(T[ch][2 * pl], T[ch][2 * pl + 1]);
    }
    return;
  }

  float (*qs)[68] = (float(*)[68])pool;
  float (*ks)[68] = (float(*)[68])(pool + 16 * 68);
  int x0 = sub * 64;
  const float* zb = z + ((size_t)bb * NCH + h * 64) * WPOS;
  for (int idx = tid; idx < 16 * 64; idx += 256) {
    int d = idx >> 6, xl = idx & 63;
    int xg = x0 + xl;
    float kv = 0.f, qv = 0.f;
    if (xg < WPOS) {
      kv = caL[d] * zb[(size_t)d * WPOS + xg] + cbL[d];
      qv = caL[16 + d] * zb[(size_t)(16 + d) * WPOS + xg] + cbL[16 + d];
    }
    ks[d][xl] = kv; qs[d][xl] = qv;
  }
  __syncthreads();
  float* outp = lpp + ((size_t)bbh * 4 + sub) * 548;
  if (tid < 16) {
    float s = 0.f;
    for (int xl = 0; xl < 64; ++xl) s += qs[tid][xl];
    outp[516 + tid] = s;
  } else if (tid < 32) {
    float s = 0.f;
    for (int xl = 0; xl < 64; ++xl) s += ks[tid - 16][xl];
    outp[532 + (tid - 16)] = s;
  }
  {
    int d = tid >> 4, d2 = tid & 15;
    float g1 = 0.f, g2 = 0.f;
    for (int xl = 0; xl < 64; ++xl) {
      g1 += qs[d][xl] * qs[d2][xl];
      g2 += ks[d][xl] * ks[d2][xl];
    }
    outp[tid] = g1;
    outp[256 + tid] = g2;
  }
  float v_sumqr = 0.f, v_sqqr = 0.f, v_sumkr = 0.f, v_sqkr = 0.f;
  for (int idx = tid; idx < 16 * 64; idx += 256) {
    int d = idx >> 6, xl = idx & 63;
    int xg = x0 + xl;
    if (xg < WPOS) {
      int ihi = 501 - xg, ilo = 250 - xg;
      float qv = qs[d][xl];
      v_sumqr += qv * (p1q[d * 502 + ihi] - p1q[d * 502 + ilo]);
      float t = 0.f;
      for (int d2 = 0; d2 < 16; ++d2) {
        const float* pp = p2q + (size_t)(d * 16 + d2) * 502;
        t += qs[d2][xl] * (pp[ihi] - pp[ilo]);
      }
      v_sqqr += qv * t;
      float kv = ks[d][xl];
      v_sumkr += kv * (p1k[d * 502 + ihi] - p1k[d * 502 + ilo]);
      float t2 = 0.f;
      for (int d2 = 0; d2 < 16; ++d2) {
        const float* pp = p2k + (size_t)(d * 16 + d2) * 502;
        t2 += ks[d2][xl] * (pp[ihi] - pp[ilo]);
      }
      v_sqkr += kv * t2;
    }
  }
  float r1 = block_reduce(v_sumqr, red, tid);
  float r2 = block_reduce(v_sqqr, red, tid);
  float r3 = block_reduce(v_sumkr, red, tid);
  float r4 = block_reduce(v_sqkr, red, tid);
  if (tid == 0) { outp[512] = r1; outp[513] = r2; outp[514] = r3; outp[515] = r4; }
}

// ---------------- K3: combine partials; atomic into lacc[24][2] ----------------
__global__ __launch_bounds__(256) void k_lstats2(const float* __restrict__ lpp,
                                                 float* __restrict__ lacc) {
  int bbh = blockIdx.x;
  int h = bbh & 7;
  int tid = threadIdx.x;
  __shared__ float red[256];
  __shared__ float qsums[16], ksums[16];
  const float* b0 = lpp + (size_t)bbh * 4 * 548;
  float qg = b0[tid] + b0[548 + tid] + b0[1096 + tid] + b0[1644 + tid];
  float kg = b0[256 + tid] + b0[804 + tid] + b0[1352 + tid] + b0[1900 + tid];
  if (tid < 16) {
    qsums[tid] = b0[516 + tid] + b0[1064 + tid] + b0[1612 + tid] + b0[2160 + tid];
    ksums[tid] = b0[532 + tid] + b0[1080 + tid] + b0[1628 + tid] + b0[2176 + tid];
  }
  float sqqk = block_reduce(qg * kg, red, tid);
  if (tid == 0) {
    float sum_qk = 0.f;
    for (int d = 0; d < 16; ++d) sum_qk += qsums[d] * ksums[d];
    float s1 = 0.f, s2 = 0.f, s3 = 0.f, s4 = 0.f;
    for (int c = 0; c < 4; ++c) {
      const float* bc = b0 + (size_t)c * 548;
      s1 += bc[512]; s2 += bc[513]; s3 += bc[514]; s4 += bc[515];
    }
    atomicAdd(&lacc[(0 * 8 + h) * 2 + 0], sum_qk);
    atomicAdd(&lacc[(0 * 8 + h) * 2 + 1], sqqk);
    atomicAdd(&lacc[(1 * 8 + h) * 2 + 0], s1);
    atomicAdd(&lacc[(1 * 8 + h) * 2 + 1], s2);
    atomicAdd(&lacc[(2 * 8 + h) * 2 + 0], s3);
    atomicAdd(&lacc[(2 * 8 + h) * 2 + 1], s4);
  }
}

// ---------------- K4: fused logits + softmax + MFMA attention ----------------
__global__ __launch_bounds__(256) void k_attn(
    const float* __restrict__ z,
    const float* __restrict__ gk, const float* __restrict__ bk,
    const float* __restrict__ gq, const float* __restrict__ bq,
    const float* __restrict__ gkq, const float* __restrict__ bkq,
    const float* __restrict__ csum, const float* __restrict__ csum2,
    const unsigned* __restrict__ vh,
    const unsigned* __restrict__ retc, const unsigned* __restrict__ vetp,
    const float* __restrict__ lacc, const float* __restrict__ glog,
    float* __restrict__ out) {
  int blk = blockIdx.x;
  int bbh = blk % 240, tile = blk / 240;
  int bb = bbh >> 3, h = bbh & 7;
  int b = bb / 15, hi = bb % 15;
  int x0 = tile * 32;
  int nr = min(32, WPOS - x0);
  int tid = threadIdx.x;
  int lane = tid & 63, wvid = tid >> 6;

  const float LOG2E = 1.4426950408889634f;

  __shared__ __align__(16) unsigned Su[32 * 132];     // fp16 S, 264 halfs/row
  __shared__ __align__(16) unsigned winU[282 * 18];   // rel rows; later Cred
  __shared__ __align__(16) unsigned uSh[256];
  __shared__ float affL[68];                          // ca[32] cb[32] la[3]
  _Float16* S = (_Float16*)Su;
  unsigned* qsP = uSh;
  float* sred = (float*)uSh;
  float* Cred = (float*)winU;

  int pwin0 = 251 - x0 - nr;
  int nwin = 250 + nr;

  // ---- inline channel affine (32 k/q channels) + logit scales ----
  if (tid < 32) {
    int ch = h * 64 + tid;
    chan_affine(ch, gk, bk, gq, bq, gkq, bkq, csum, csum2, affL[tid], affL[32 + tid]);
  } else if (tid < 35) {
    int grp = tid - 32;
    int c = grp * 8 + h;
    float n = (float)NBB * (float)WPOS * (float)WPOS;
    float mean = lacc[c * 2] / n;
    float var = lacc[c * 2 + 1] / n - mean * mean;
    affL[64 + grp] = glog[c] / sqrtf(var + NEPS) * LOG2E;
  }
  __syncthreads();
  float la_qk = affL[64], la_qr = affL[65], la_kr = affL[66];

  const float* zb = z + ((size_t)bb * NCH + h * 64) * WPOS;

  // ---- stage rel window into LDS ----
  for (int i = tid; i < nwin * 16; i += 256) {
    int r = i >> 4, j = i & 15;
    winU[r * 18 + j] = retc[(size_t)(pwin0 + r) * 16 + j];
  }

  // ---- stage q tile (affine from raw z, fp16-packed) ----
  {
    int xx = tid & 31, j = tid >> 5;
    int xcl = min(x0 + xx, WPOS - 1);
    float q0 = affL[16 + 2 * j] * zb[(size_t)(16 + 2 * j) * WPOS + xcl] + affL[48 + 2 * j];
    float q1 = affL[17 + 2 * j] * zb[(size_t)(17 + 2 * j) * WPOS + xcl] + affL[49 + 2 * j];
    qsP[xx * 8 + j] = packh2(q0, q1);
  }

  // ---- k row per lane (affine from raw z), fp16-packed ----
  int yy = wvid * 64 + lane;
  int yc = min(yy, WPOS - 1);
  bool yok = (yy < WPOS);
  half2_t khv[8];
#pragma unroll
  for (int d = 0; d < 8; ++d) {
    float k0 = affL[2 * d]     * zb[(size_t)(2 * d) * WPOS + yc] + affL[32 + 2 * d];
    float k1 = affL[2 * d + 1] * zb[(size_t)(2 * d + 1) * WPOS + yc] + affL[33 + 2 * d];
    khv[d] = __builtin_bit_cast(half2_t, packh2(k0, k1));
  }
  __syncthreads();

  // ---- fused S: qk + qr + kr, log2 domain; lanes on y, loop over x ----
  {
    int rowbase = yc + nr - 1;
    for (int xx = 0; xx < nr; ++xx) {
      const unsigned* wr = &winU[(size_t)(rowbase - xx) * 18];
      const unsigned* qp = &qsP[xx * 8];
      float dqk = 0.f, dqr = 0.f, dkr = 0.f;
#pragma unroll
      for (int j2 = 0; j2 < 4; ++j2) {
        uint2 ue = *(const uint2*)(wr + 2 * j2);
        uint2 uk = *(const uint2*)(wr + 8 + 2 * j2);
        uint2 uq = *(const uint2*)(qp + 2 * j2);
        half2_t qe0 = ash2(ue.x), qe1 = ash2(ue.y);
        half2_t ke0 = ash2(uk.x), ke1 = ash2(uk.y);
        half2_t q0  = ash2(uq.x), q1  = ash2(uq.y);
        half2_t k0 = khv[2 * j2], k1 = khv[2 * j2 + 1];
        dqk = FDOT2(q0, k0, dqk);  dqk = FDOT2(q1, k1, dqk);
        dqr = FDOT2(q0, qe0, dqr); dqr = FDOT2(q1, qe1, dqr);
        dkr = FDOT2(k0, ke0, dkr); dkr = FDOT2(k1, ke1, dkr);
      }
      float sval = la_qk * dqk + la_qr * dqr + la_kr * dkr;
      S[xx * 264 + yy] = yok ? (_Float16)sval : (_Float16)0.f;
    }
  }
  // ---- zero pad: cols 256..263; full rows nr..31 (tile 7) ----
  for (int i = tid; i < 32 * 8; i += 256)
    S[(i >> 3) * 264 + 256 + (i & 7)] = (_Float16)0.f;
  if (nr < 32) {
    int ntail = (32 - nr) * 264;
    for (int i = tid; i < ntail; i += 256) S[nr * 264 + i] = (_Float16)0.f;
  }
  __syncthreads();

  // ---- softmax over y; lanes on x, 8 slices; pair-wise fp16 ----
  int xx = lane & 31;
  int sl = wvid * 2 + (lane >> 5);
  int ylo = sl * 32;
  const unsigned* Srp = Su + xx * 132;
  {
    float m = -1e30f;
    if (sl < 7) {
#pragma unroll
      for (int pp = 0; pp < 16; ++pp) {
        half2_t hp = ash2(Srp[(ylo >> 1) + pp]);
        m = fmaxf(m, fmaxf((float)hp[0], (float)hp[1]));
      }
    } else {
#pragma unroll
      for (int pp = 0; pp < 13; ++pp) {
        half2_t hp = ash2(Srp[112 + pp]);
        m = fmaxf(m, fmaxf((float)hp[0], (float)hp[1]));
      }
      m = fmaxf(m, (float)S[xx * 264 + 250]);
    }
    sred[sl * 32 + xx] = m;
  }
  __syncthreads();
  float rowm = sred[0 * 32 + xx];
#pragma unroll
  for (int s = 1; s < 8; ++s) rowm = fmaxf(rowm, sred[s * 32 + xx]);
  __syncthreads();
  {
    float sacc = 0.f;
    unsigned* Swp = Su + xx * 132;
    if (sl < 7) {
#pragma unroll
      for (int pp = 0; pp < 16; ++pp) {
        half2_t hp = ash2(Swp[(ylo >> 1) + pp]);
        float e0 = exp2f((float)hp[0] - rowm);
        float e1 = exp2f((float)hp[1] - rowm);
        Swp[(ylo >> 1) + pp] = packh2(e0, e1);
        sacc += e0 + e1;
      }
    } else {
#pragma unroll
      for (int pp = 0; pp < 13; ++pp) {
        half2_t hp = ash2(Swp[112 + pp]);
        float e0 = exp2f((float)hp[0] - rowm);
        float e1 = exp2f((float)hp[1] - rowm);
        Swp[112 + pp] = packh2(e0, e1);
        sacc += e0 + e1;
      }
      float e = exp2f((float)S[xx * 264 + 250] - rowm);
      S[xx * 264 + 250] = (_Float16)e;
      sacc += e;
    }
    sred[sl * 32 + xx] = sacc;
  }
  __syncthreads();
  float denom = 0.f;
#pragma unroll
  for (int s = 0; s < 8; ++s) denom += sred[s * 32 + xx];

  // ---- MFMA PV: C[d][x]; K-split across 4 waves ----
  f32x16_t acc = {};
  int xcol = lane & 31;
  int khh = lane >> 5;
  const _Float16* Srow = S + xcol * 264;
  {
    const unsigned* vhb = vh + (size_t)bbh * 128 * 32 + xcol;
#pragma unroll
    for (int ks = 0; ks < 4; ++ks) {
      int y0 = 64 * wvid + 16 * ks + 8 * khh;
      int t0 = y0 >> 1;
      uint4 au = {vhb[(size_t)(t0 + 0) * 32], vhb[(size_t)(t0 + 1) * 32],
                  vhb[(size_t)(t0 + 2) * 32], vhb[(size_t)(t0 + 3) * 32]};
      half8_t af = __builtin_bit_cast(half8_t, au);
      half8_t bf = *(const half8_t*)(Srow + y0);
      acc = __builtin_amdgcn_mfma_f32_32x32x16_f16(af, bf, acc, 0, 0, 0);
    }
    const unsigned* vpb = vetp + xcol;
    int ybase = xcol + x0 - 250;
#pragma unroll
    for (int ks = 0; ks < 8; ++ks) {
      int p0 = 128 * wvid + 16 * ks + 8 * khh;
      int t0 = p0 >> 1;
      uint4 au = {vpb[(size_t)(t0 + 0) * 32], vpb[(size_t)(t0 + 1) * 32],
                  vpb[(size_t)(t0 + 2) * 32], vpb[(size_t)(t0 + 3) * 32]};
      half8_t af = __builtin_bit_cast(half8_t, au);
      half8_t bf;
#pragma unroll
      for (int e = 0; e < 8; ++e) {
        int yv = ybase + p0 + e;
        bf[e] = ((unsigned)yv < 264u) ? Srow[yv] : (_Float16)0.f;
      }
      acc = __builtin_amdgcn_mfma_f32_32x32x16_f16(af, bf, acc, 0, 0, 0);
    }
  }

  // ---- cross-wave C reduction via Cred (winU space), wave 0 stores ----
  if (wvid > 0) {
    float* cp = Cred + ((size_t)(wvid - 1) * 64 + lane) * 17;
#pragma unroll
    for (int r = 0; r < 16; ++r) cp[r] = acc[r];
  }
  __syncthreads();
  if (wvid == 0) {
#pragma unroll
    for (int w2 = 0; w2 < 3; ++w2) {
      const float* cp = Cred + ((size_t)w2 * 64 + lane) * 17;
#pragma unroll
      for (int r = 0; r < 16; ++r) acc[r] += cp[r];
    }
    if (xcol < nr) {
      float rinv = 1.0f / denom;
      int xg = x0 + xcol;
#pragma unroll
      for (int r = 0; r < 16; ++r) {
        int d = (r & 3) + 8 * (r >> 2) + 4 * khh;
        out[(((size_t)b * 256 + h * 32 + d) * 15 + hi) * WPOS + xg] = acc[r] * rinv;
      }
    }
  }
}

// ---------------- launch ----------------
extern "C" void kernel_launch(void* const* d_in, const int* in_sizes, int n_in,
                              void* d_out, int out_size, void* d_ws, size_t ws_size,
                              hipStream_t stream) {
  const float* x    = (const float*)d_in[0];
  const float* y    = (const float*)d_in[1];
  const float* wk   = (const float*)d_in[2];
  const float* wq   = (const float*)d_in[3];
  const float* wv   = (const float*)d_in[4];
  const float* gk   = (const float*)d_in[5];
  const float* bk   = (const float*)d_in[6];
  const float* gq   = (const float*)d_in[7];
  const float* bq   = (const float*)d_in[8];
  const float* gkq  = (const float*)d_in[9];
  const float* bkq  = (const float*)d_in[10];
  const float* glog = (const float*)d_in[11];
  const float* rel  = (const float*)d_in[13];
  float* out = (float*)d_out;
  float* ws  = (float*)d_ws;

  float* z      = ws + OFF_Z;
  unsigned* vh  = (unsigned*)(ws + OFF_VH);
  unsigned* retc= (unsigned*)(ws + OFF_RETC);
  unsigned* vetp= (unsigned*)(ws + OFF_VETP);
  float* p1q    = ws + OFF_P1Q;
  float* p1k    = ws + OFF_P1K;
  float* p2q    = ws + OFF_P2Q;
  float* p2k    = ws + OFF_P2K;
  float* lpp    = ws + OFF_LPP;
  float* csum   = ws + OFF_ACC;
  float* csum2  = csum + 512;
  float* lacc   = csum2 + 512;

  hipMemsetAsync(csum, 0, (512 + 512 + 48) * sizeof(float), stream);
  k_pre<<<608, 256, 0, stream>>>(rel, retc, vetp, p1q, p1k, p2q, p2k);
  dim3 g1(4, 8, NBB);
  k_gemm<<<g1, 256, 0, stream>>>(x, y, wk, wq, wv, z, csum, csum2);
  k_mid<<<1920, 256, 0, stream>>>(z, gk, bk, gq, bq, gkq, bkq, csum, csum2,
                                  vh, p1q, p1k, p2q, p2k, lpp);
  k_lstats2<<<240, 256, 0, stream>>>(lpp, lacc);
  k_attn<<<240 * 8, 256, 0, stream>>>(z, gk, bk, gq, bq, gkq, bkq, csum, csum2,
                                      vh, retc, vetp, lacc, glog, out);
}

// Round 11
// 110.209 us; speedup vs baseline: 1.4508x; 1.4508x over previous
//
#include <hip/hip_runtime.h>
#include <hip/hip_bf16.h>
#include <cstdint>

#define WPOS 251
#define NBB  30
#define NCH  512
#define RELP 501
#define NEPS 1e-5f

typedef _Float16 half2_t __attribute__((ext_vector_type(2)));
typedef _Float16 half8_t __attribute__((ext_vector_type(8)));
typedef float f32x16_t __attribute__((ext_vector_type(16)));

#if defined(__has_builtin)
#if __has_builtin(__builtin_amdgcn_fdot2)
#define FDOT2(a, b, c) __builtin_amdgcn_fdot2((a), (b), (c), false)
#endif
#endif
#ifndef FDOT2
#define FDOT2(a, b, c) ((float)(a)[0] * (float)(b)[0] + (float)(a)[1] * (float)(b)[1] + (c))
#endif

// ---------------- workspace layout (in float slots) ----------------
static constexpr size_t SZ_Z     = (size_t)NBB * NCH * WPOS;
static constexpr size_t OFF_Z    = 0;
static constexpr size_t OFF_VH   = OFF_Z + SZ_Z;                   // uint[bbh][128][32] half2 v pairs
static constexpr size_t SZ_VH    = (size_t)NBB * 8 * 128 * 32;
static constexpr size_t OFF_RETC = OFF_VH + SZ_VH;                 // uint[501][16]: qe|keR fp16 pairs
static constexpr size_t OFF_VETP = OFF_RETC + (size_t)RELP * 16;   // uint[256][32] half2 p-pairs
static constexpr size_t OFF_P1Q  = OFF_VETP + (size_t)256 * 32;    // [16][502]
static constexpr size_t OFF_P1K  = OFF_P1Q + (size_t)16 * 502;
static constexpr size_t OFF_P2Q  = OFF_P1K + (size_t)16 * 502;     // [256][502]
static constexpr size_t OFF_P2K  = OFF_P2Q + (size_t)256 * 502;
static constexpr size_t OFF_LPP  = OFF_P2K + (size_t)256 * 502;    // [960][548] partials
static constexpr size_t OFF_CPS  = OFF_LPP + (size_t)960 * 548;    // [240][512] channel sum partials
static constexpr size_t OFF_CPS2 = OFF_CPS + (size_t)240 * 512;    // [240][512]
static constexpr size_t OFF_CS   = OFF_CPS2 + (size_t)240 * 512;   // csum[512]
static constexpr size_t OFF_CS2  = OFF_CS + 512;                   // csum2[512]
static constexpr size_t OFF_LPF  = OFF_CS2 + 512;                  // lp[240][6]

static __device__ __forceinline__ unsigned packh2(float a, float b) {
  half2_t t;
  t[0] = (_Float16)a;
  t[1] = (_Float16)b;
  return __builtin_bit_cast(unsigned, t);
}
static __device__ __forceinline__ half2_t ash2(unsigned u) {
  return __builtin_bit_cast(half2_t, u);
}

// ---------------- K0: rel prep (64 blocks) + prefix scans (544 blocks) ----------------
__global__ __launch_bounds__(256) void k_pre(
    const float* __restrict__ rel, unsigned* __restrict__ retc, unsigned* __restrict__ vetp,
    float* __restrict__ p1q, float* __restrict__ p1k,
    float* __restrict__ p2q, float* __restrict__ p2k) {
  int blk = blockIdx.x;
  if (blk < 64) {
    int idx = blk * 256 + threadIdx.x;
    if (idx < RELP * 16) {
      int p = idx >> 4, j = idx & 15;
      float lo, hi;
      if (j < 8) {
        lo = rel[(size_t)(2 * j) * RELP + p];
        hi = rel[(size_t)(2 * j + 1) * RELP + p];
      } else {
        int jj = j - 8;
        lo = rel[(size_t)(16 + 2 * jj) * RELP + (500 - p)];
        hi = rel[(size_t)(17 + 2 * jj) * RELP + (500 - p)];
      }
      retc[(size_t)p * 16 + j] = packh2(lo, hi);
    } else if (idx < RELP * 16 + 256 * 32) {
      int i2 = idx - RELP * 16;
      int t = i2 >> 5, ch = i2 & 31;
      float lo = (2 * t <= 500) ? rel[(size_t)(32 + ch) * RELP + 2 * t] : 0.f;
      float hi = (2 * t + 1 <= 500) ? rel[(size_t)(32 + ch) * RELP + 2 * t + 1] : 0.f;
      vetp[(size_t)t * 32 + ch] = packh2(lo, hi);
    }
    return;
  }
  int task = blk - 64;   // 0..543
  const float* ra;
  const float* rb = nullptr;
  float* outp;
  if (task < 16)        { ra = rel + (size_t)task * RELP; outp = p1q + (size_t)task * 502; }
  else if (task < 32)   { ra = rel + (size_t)task * RELP; outp = p1k + (size_t)(task - 16) * 502; }
  else if (task < 288)  { int pr = task - 32;
                          ra = rel + (size_t)(pr >> 4) * RELP;
                          rb = rel + (size_t)(pr & 15) * RELP;
                          outp = p2q + (size_t)pr * 502; }
  else                  { int pr = task - 288;
                          ra = rel + (size_t)(16 + (pr >> 4)) * RELP;
                          rb = rel + (size_t)(16 + (pr & 15)) * RELP;
                          outp = p2k + (size_t)pr * 502; }
  __shared__ float buf[256];
  int t = threadIdx.x;
  int i0 = 2 * t, i1 = 2 * t + 1;
  float a0 = (i0 < RELP) ? (rb ? ra[i0] * rb[i0] : ra[i0]) : 0.f;
  float a1 = (i1 < RELP) ? (rb ? ra[i1] * rb[i1] : ra[i1]) : 0.f;
  buf[t] = a0 + a1;
  __syncthreads();
#pragma unroll
  for (int off = 1; off < 256; off <<= 1) {
    float v = buf[t];
    float add = (t >= off) ? buf[t - off] : 0.f;
    __syncthreads();
    buf[t] = v + add;
    __syncthreads();
  }
  float ex = buf[t] - (a0 + a1);
  if (i0 <= RELP) outp[i0] = ex;
  if (i1 <= RELP) outp[i1] = ex + a0;
}

// ---------------- K1: kqv GEMM via fp16 MFMA + contention-free stat partials ----------------
__global__ __launch_bounds__(256) void k_gemm(
    const float* __restrict__ x, const float* __restrict__ y,
    const float* __restrict__ wk, const float* __restrict__ wq,
    const float* __restrict__ wv, float* __restrict__ z,
    float* __restrict__ cps, float* __restrict__ cps2) {
  int l0 = blockIdx.x * 64;
  int o0 = blockIdx.y * 64;
  int bb = blockIdx.z;
  int b = bb / 15, hi = bb % 15;
  const float* src;
  const float* wmat;
  int orow0;
  if (o0 < 128)      { wmat = wk; orow0 = o0;       src = x; }
  else if (o0 < 256) { wmat = wq; orow0 = o0 - 128; src = y; }
  else               { wmat = wv; orow0 = o0 - 256; src = x; }

  __shared__ _Float16 Ah[64][68];   // [o][k]
  __shared__ _Float16 Bh[64][68];   // [k][l]

  int tid = threadIdx.x;
  int lane = tid & 63, wv4 = tid >> 6;
  int wo = wv4 >> 1, wl = wv4 & 1;
  int m = lane & 31, kh = lane >> 5;

  f32x16_t acc = {};

  int cA = tid & 63, ogA = tid >> 6;
  int lB = tid & 63, kgB = tid >> 6;
  int lglob = l0 + lB;
  bool lok = (lglob < WPOS);
  const float* xcol = src + (size_t)(((size_t)b * 256) * 15 + hi) * WPOS + lglob;

  for (int c0 = 0; c0 < 256; c0 += 64) {
#pragma unroll
    for (int i = 0; i < 16; ++i) {
      int o = ogA * 16 + i;
      Ah[o][cA] = (_Float16)wmat[(size_t)(orow0 + o) * 256 + c0 + cA];
    }
#pragma unroll
    for (int i = 0; i < 16; ++i) {
      int k = kgB * 16 + i;
      float v = lok ? xcol[(size_t)(c0 + k) * 15 * WPOS] : 0.f;
      Bh[k][lB] = (_Float16)v;
    }
    __syncthreads();
#pragma unroll
    for (int ks = 0; ks < 4; ++ks) {
      const _Float16* ap = &Ah[wo * 32 + m][ks * 16 + kh * 8];
      uint2 aLo = *(const uint2*)(ap);
      uint2 aHi = *(const uint2*)(ap + 4);
      uint4 au = {aLo.x, aLo.y, aHi.x, aHi.y};
      half8_t af = __builtin_bit_cast(half8_t, au);
      half8_t bf;
      int kb = ks * 16 + kh * 8;
      int bcol = wl * 32 + m;
#pragma unroll
      for (int e = 0; e < 8; ++e) bf[e] = Bh[kb + e][bcol];
      acc = __builtin_amdgcn_mfma_f32_32x32x16_f16(af, bf, acc, 0, 0, 0);
    }
    __syncthreads();
  }

  int n = lane & 31;
  int lout = l0 + wl * 32 + n;
  if (lout < WPOS) {
#pragma unroll
    for (int r = 0; r < 16; ++r) {
      int mrow = (r & 3) + 8 * (r >> 2) + 4 * kh;
      int o = o0 + wo * 32 + mrow;
      z[((size_t)bb * NCH + o) * WPOS + lout] = acc[r];
    }
  }

  // ---- channel partial sums: single writer per (part, o) -> no atomics ----
  int part = (blockIdx.x * 2 + wl) * NBB + bb;
#pragma unroll
  for (int r = 0; r < 16; ++r) {
    float s = acc[r];
    float s2 = s * s;
#pragma unroll
    for (int m2 = 1; m2 < 32; m2 <<= 1) {
      s  += __shfl_xor(s, m2, 64);
      s2 += __shfl_xor(s2, m2, 64);
    }
    if (n == 0) {
      int mrow = (r & 3) + 8 * (r >> 2) + 4 * kh;
      int o = o0 + wo * 32 + mrow;
      cps[(size_t)part * 512 + o] = s;
      cps2[(size_t)part * 512 + o] = s2;
    }
  }
}

// ---------------- K1b: reduce 240 channel partials -> csum/csum2 ----------------
__global__ __launch_bounds__(256) void k_cred(
    const float* __restrict__ cps, const float* __restrict__ cps2,
    float* __restrict__ csum, float* __restrict__ csum2) {
  int c = blockIdx.x * 16 + (threadIdx.x & 15);
  int grp = threadIdx.x >> 4;           // 16 groups x 15 parts = 240
  __shared__ float r1[256], r2[256];
  float s = 0.f, s2 = 0.f;
  for (int i = 0; i < 15; ++i) {
    int p = grp * 15 + i;
    s += cps[(size_t)p * 512 + c];
    s2 += cps2[(size_t)p * 512 + c];
  }
  r1[threadIdx.x] = s; r2[threadIdx.x] = s2;
  __syncthreads();
  for (int st = 128; st >= 16; st >>= 1) {
    if (threadIdx.x < st) {
      r1[threadIdx.x] += r1[threadIdx.x + st];
      r2[threadIdx.x] += r2[threadIdx.x + st];
    }
    __syncthreads();
  }
  if (threadIdx.x < 16) {
    csum[c] = r1[threadIdx.x];
    csum2[c] = r2[threadIdx.x];
  }
}

// ---------------- helpers ----------------
__device__ __forceinline__ float block_reduce(float v, float* red, int tid) {
  red[tid] = v; __syncthreads();
  for (int s = 128; s > 0; s >>= 1) {
    if (tid < s) red[tid] += red[tid + s];
    __syncthreads();
  }
  float r = red[0]; __syncthreads();
  return r;
}

__device__ __forceinline__ void chan_affine(
    int ch, const float* gk, const float* bk, const float* gq, const float* bq,
    const float* gkq, const float* bkq, const float* csum, const float* csum2,
    float& a, float& bout) {
  float g, bi;
  if (ch < 128)      { g = gk[ch];        bi = bk[ch]; }
  else if (ch < 256) { g = gq[ch - 128];  bi = bq[ch - 128]; }
  else               { g = gkq[ch - 256]; bi = bkq[ch - 256]; }
  float n = (float)(NBB * WPOS);
  float mean = csum[ch] / n;
  float var = csum2[ch] / n - mean * mean;
  a = g / sqrtf(var + NEPS);
  bout = bi - mean * a;
}

// ---------------- K2: merged norm_vh (blocks 0..959) + lstats1 (960..1919) ----------------
__global__ __launch_bounds__(256) void k_mid(
    const float* __restrict__ z,
    const float* __restrict__ gk, const float* __restrict__ bk,
    const float* __restrict__ gq, const float* __restrict__ bq,
    const float* __restrict__ gkq, const float* __restrict__ bkq,
    const float* __restrict__ csum, const float* __restrict__ csum2,
    unsigned* __restrict__ vh,
    const float* __restrict__ p1q, const float* __restrict__ p1k,
    const float* __restrict__ p2q, const float* __restrict__ p2k,
    float* __restrict__ lpp) {
  int blk = blockIdx.x;
  bool isV = (blk < 960);
  int sblk = isV ? blk : blk - 960;
  int bbh = sblk % 240, sub = sblk / 240;
  int bb = bbh >> 3, h = bbh & 7;
  int tid = threadIdx.x;

  __shared__ __align__(16) float pool[16 * 68 * 2];
  __shared__ float red[256];
  __shared__ float caL[32], cbL[32];

  if (tid < 32) {
    int ch = h * 64 + (isV ? 32 + tid : tid);
    chan_affine(ch, gk, bk, gq, bq, gkq, bkq, csum, csum2, caL[tid], cbL[tid]);
  }
  __syncthreads();

  if (isV) {
    float (*T)[65] = (float(*)[65])pool;
    int l0 = sub * 64;
    const float* zv = z + ((size_t)bb * NCH + h * 64 + 32) * WPOS;
    for (int i = tid; i < 32 * 64; i += 256) {
      int ch = i >> 6, l = i & 63;
      int gl = l0 + l;
      T[ch][l] = (gl < WPOS) ? (caL[ch] * zv[(size_t)ch * WPOS + gl] + cbL[ch]) : 0.f;
    }
    __syncthreads();
    int p0 = l0 >> 1;
    for (int i = tid; i < 32 * 32; i += 256) {
      int pl = i >> 5, ch = i & 31;
      int gp = p0 + pl;
      if (gp < 128)
        vh[((size_t)bbh * 128 + gp) * 32 + ch] = packh2(T[ch][2 * pl], T[ch][2 * pl + 1]);
    }
    return;
  }

  float (*qs)[68] = (float(*)[68])pool;
  float (*ks)[68] = (float(*)[68])(pool + 16 * 68);
  int x0 = sub * 64;
  const float* zb = z + ((size_t)bb * NCH + h * 64) * WPOS;
  for (int idx = tid; idx < 16 * 64; idx += 256) {
    int d = idx >> 6, xl = idx & 63;
    int xg = x0 + xl;
    float kv = 0.f, qv = 0.f;
    if (xg < WPOS) {
      kv = caL[d] * zb[(size_t)d * WPOS + xg] + cbL[d];
      qv = caL[16 + d] * zb[(size_t)(16 + d) * WPOS + xg] + cbL[16 + d];
    }
    ks[d][xl] = kv; qs[d][xl] = qv;
  }
  __syncthreads();
  float* outp = lpp + ((size_t)bbh * 4 + sub) * 548;
  if (tid < 16) {
    float s = 0.f;
    for (int xl = 0; xl < 64; ++xl) s += qs[tid][xl];
    outp[516 + tid] = s;
  } else if (tid < 32) {
    float s = 0.f;
    for (int xl = 0; xl < 64; ++xl) s += ks[tid - 16][xl];
    outp[532 + (tid - 16)] = s;
  }
  {
    int d = tid >> 4, d2 = tid & 15;
    float g1 = 0.f, g2 = 0.f;
    for (int xl = 0; xl < 64; ++xl) {
      g1 += qs[d][xl] * qs[d2][xl];
      g2 += ks[d][xl] * ks[d2][xl];
    }
    outp[tid] = g1;
    outp[256 + tid] = g2;
  }
  float v_sumqr = 0.f, v_sqqr = 0.f, v_sumkr = 0.f, v_sqkr = 0.f;
  for (int idx = tid; idx < 16 * 64; idx += 256) {
    int d = idx >> 6, xl = idx & 63;
    int xg = x0 + xl;
    if (xg < WPOS) {
      int ihi = 501 - xg, ilo = 250 - xg;
      float qv = qs[d][xl];
      v_sumqr += qv * (p1q[d * 502 + ihi] - p1q[d * 502 + ilo]);
      float t = 0.f;
      for (int d2 = 0; d2 < 16; ++d2) {
        const float* pp = p2q + (size_t)(d * 16 + d2) * 502;
        t += qs[d2][xl] * (pp[ihi] - pp[ilo]);
      }
      v_sqqr += qv * t;
      float kv = ks[d][xl];
      v_sumkr += kv * (p1k[d * 502 + ihi] - p1k[d * 502 + ilo]);
      float t2 = 0.f;
      for (int d2 = 0; d2 < 16; ++d2) {
        const float* pp = p2k + (size_t)(d * 16 + d2) * 502;
        t2 += ks[d2][xl] * (pp[ihi] - pp[ilo]);
      }
      v_sqkr += kv * t2;
    }
  }
  float r1 = block_reduce(v_sumqr, red, tid);
  float r2 = block_reduce(v_sqqr, red, tid);
  float r3 = block_reduce(v_sumkr, red, tid);
  float r4 = block_reduce(v_sqkr, red, tid);
  if (tid == 0) { outp[512] = r1; outp[513] = r2; outp[514] = r3; outp[515] = r4; }
}

// ---------------- K3: combine partials -> lp[bbh][6] (plain writes) ----------------
__global__ __launch_bounds__(256) void k_lstats2(const float* __restrict__ lpp,
                                                 float* __restrict__ lp) {
  int bbh = blockIdx.x;
  int tid = threadIdx.x;
  __shared__ float red[256];
  __shared__ float qsums[16], ksums[16];
  const float* b0 = lpp + (size_t)bbh * 4 * 548;
  float qg = b0[tid] + b0[548 + tid] + b0[1096 + tid] + b0[1644 + tid];
  float kg = b0[256 + tid] + b0[804 + tid] + b0[1352 + tid] + b0[1900 + tid];
  if (tid < 16) {
    qsums[tid] = b0[516 + tid] + b0[1064 + tid] + b0[1612 + tid] + b0[2160 + tid];
    ksums[tid] = b0[532 + tid] + b0[1080 + tid] + b0[1628 + tid] + b0[2176 + tid];
  }
  float sqqk = block_reduce(qg * kg, red, tid);
  if (tid == 0) {
    float sum_qk = 0.f;
    for (int d = 0; d < 16; ++d) sum_qk += qsums[d] * ksums[d];
    float s1 = 0.f, s2 = 0.f, s3 = 0.f, s4 = 0.f;
    for (int c = 0; c < 4; ++c) {
      const float* bc = b0 + (size_t)c * 548;
      s1 += bc[512]; s2 += bc[513]; s3 += bc[514]; s4 += bc[515];
    }
    float* o = lp + (size_t)bbh * 6;
    o[0] = sum_qk; o[1] = sqqk;
    o[2] = s1; o[3] = s2; o[4] = s3; o[5] = s4;
  }
}

// ---------------- K4: fused logits + softmax + MFMA attention ----------------
__global__ __launch_bounds__(256) void k_attn(
    const float* __restrict__ z,
    const float* __restrict__ gk, const float* __restrict__ bk,
    const float* __restrict__ gq, const float* __restrict__ bq,
    const float* __restrict__ gkq, const float* __restrict__ bkq,
    const float* __restrict__ csum, const float* __restrict__ csum2,
    const unsigned* __restrict__ vh,
    const unsigned* __restrict__ retc, const unsigned* __restrict__ vetp,
    const float* __restrict__ lp, const float* __restrict__ glog,
    float* __restrict__ out) {
  int blk = blockIdx.x;
  int bbh = blk % 240, tile = blk / 240;
  int bb = bbh >> 3, h = bbh & 7;
  int b = bb / 15, hi = bb % 15;
  int x0 = tile * 32;
  int nr = min(32, WPOS - x0);
  int tid = threadIdx.x;
  int lane = tid & 63, wvid = tid >> 6;

  const float LOG2E = 1.4426950408889634f;

  __shared__ __align__(16) unsigned Su[32 * 132];     // fp16 S, 264 halfs/row
  __shared__ __align__(16) unsigned winU[282 * 18];   // rel rows; later Cred
  __shared__ __align__(16) unsigned uSh[256];
  __shared__ float affL[72];                          // ca[32] cb[32] lsums[6]
  _Float16* S = (_Float16*)Su;
  unsigned* qsP = uSh;
  float* sred = (float*)uSh;
  float* Cred = (float*)winU;

  int pwin0 = 251 - x0 - nr;
  int nwin = 250 + nr;

  // ---- inline channel affine + logit stat sums over bb ----
  if (tid < 32) {
    int ch = h * 64 + tid;
    chan_affine(ch, gk, bk, gq, bq, gkq, bkq, csum, csum2, affL[tid], affL[32 + tid]);
  } else if (tid >= 64 && tid < 70) {
    int grp = (tid - 64) >> 1, off = (tid - 64) & 1;
    float s = 0.f;
    for (int bb2 = 0; bb2 < NBB; ++bb2)
      s += lp[(size_t)(bb2 * 8 + h) * 6 + grp * 2 + off];
    affL[64 + (tid - 64)] = s;
  }
  __syncthreads();
  float la_qk, la_qr, la_kr;
  {
    float n = (float)NBB * (float)WPOS * (float)WPOS;
    float m0 = affL[64] / n, v0 = affL[65] / n - m0 * m0;
    float m1 = affL[66] / n, v1 = affL[67] / n - m1 * m1;
    float m2 = affL[68] / n, v2 = affL[69] / n - m2 * m2;
    la_qk = glog[0 * 8 + h] / sqrtf(v0 + NEPS) * LOG2E;
    la_qr = glog[1 * 8 + h] / sqrtf(v1 + NEPS) * LOG2E;
    la_kr = glog[2 * 8 + h] / sqrtf(v2 + NEPS) * LOG2E;
  }

  const float* zb = z + ((size_t)bb * NCH + h * 64) * WPOS;

  // ---- stage rel window into LDS ----
  for (int i = tid; i < nwin * 16; i += 256) {
    int r = i >> 4, j = i & 15;
    winU[r * 18 + j] = retc[(size_t)(pwin0 + r) * 16 + j];
  }

  // ---- stage q tile (affine from raw z, fp16-packed) ----
  {
    int xx = tid & 31, j = tid >> 5;
    int xcl = min(x0 + xx, WPOS - 1);
    float q0 = affL[16 + 2 * j] * zb[(size_t)(16 + 2 * j) * WPOS + xcl] + affL[48 + 2 * j];
    float q1 = affL[17 + 2 * j] * zb[(size_t)(17 + 2 * j) * WPOS + xcl] + affL[49 + 2 * j];
    qsP[xx * 8 + j] = packh2(q0, q1);
  }

  // ---- k row per lane (affine from raw z), fp16-packed ----
  int yy = wvid * 64 + lane;
  int yc = min(yy, WPOS - 1);
  bool yok = (yy < WPOS);
  half2_t khv[8];
#pragma unroll
  for (int d = 0; d < 8; ++d) {
    float k0 = affL[2 * d]     * zb[(size_t)(2 * d) * WPOS + yc] + affL[32 + 2 * d];
    float k1 = affL[2 * d + 1] * zb[(size_t)(2 * d + 1) * WPOS + yc] + affL[33 + 2 * d];
    khv[d] = __builtin_bit_cast(half2_t, packh2(k0, k1));
  }
  __syncthreads();

  // ---- fused S: qk + qr + kr, log2 domain; lanes on y, loop over x ----
  {
    int rowbase = yc + nr - 1;
    for (int xx = 0; xx < nr; ++xx) {
      const unsigned* wr = &winU[(size_t)(rowbase - xx) * 18];
      const unsigned* qp = &qsP[xx * 8];
      float dqk = 0.f, dqr = 0.f, dkr = 0.f;
#pragma unroll
      for (int j2 = 0; j2 < 4; ++j2) {
        uint2 ue = *(const uint2*)(wr + 2 * j2);
        uint2 uk = *(const uint2*)(wr + 8 + 2 * j2);
        uint2 uq = *(const uint2*)(qp + 2 * j2);
        half2_t qe0 = ash2(ue.x), qe1 = ash2(ue.y);
        half2_t ke0 = ash2(uk.x), ke1 = ash2(uk.y);
        half2_t q0  = ash2(uq.x), q1  = ash2(uq.y);
        half2_t k0 = khv[2 * j2], k1 = khv[2 * j2 + 1];
        dqk = FDOT2(q0, k0, dqk);  dqk = FDOT2(q1, k1, dqk);
        dqr = FDOT2(q0, qe0, dqr); dqr = FDOT2(q1, qe1, dqr);
        dkr = FDOT2(k0, ke0, dkr); dkr = FDOT2(k1, ke1, dkr);
      }
      float sval = la_qk * dqk + la_qr * dqr + la_kr * dkr;
      S[xx * 264 + yy] = yok ? (_Float16)sval : (_Float16)0.f;
    }
  }
  // ---- zero pad: cols 256..263; full rows nr..31 (tile 7) ----
  for (int i = tid; i < 32 * 8; i += 256)
    S[(i >> 3) * 264 + 256 + (i & 7)] = (_Float16)0.f;
  if (nr < 32) {
    int ntail = (32 - nr) * 264;
    for (int i = tid; i < ntail; i += 256) S[nr * 264 + i] = (_Float16)0.f;
  }
  __syncthreads();

  // ---- softmax over y; lanes on x, 8 slices; pair-wise fp16 ----
  int xx = lane & 31;
  int sl = wvid * 2 + (lane >> 5);
  int ylo = sl * 32;
  const unsigned* Srp = Su + xx * 132;
  {
    float m = -1e30f;
    if (sl < 7) {
#pragma unroll
      for (int pp = 0; pp < 16; ++pp) {
        half2_t hp = ash2(Srp[(ylo >> 1) + pp]);
        m = fmaxf(m, fmaxf((float)hp[0], (float)hp[1]));
      }
    } else {
#pragma unroll
      for (int pp = 0; pp < 13; ++pp) {
        half2_t hp = ash2(Srp[112 + pp]);
        m = fmaxf(m, fmaxf((float)hp[0], (float)hp[1]));
      }
      m = fmaxf(m, (float)S[xx * 264 + 250]);
    }
    sred[sl * 32 + xx] = m;
  }
  __syncthreads();
  float rowm = sred[0 * 32 + xx];
#pragma unroll
  for (int s = 1; s < 8; ++s) rowm = fmaxf(rowm, sred[s * 32 + xx]);
  __syncthreads();
  {
    float sacc = 0.f;
    unsigned* Swp = Su + xx * 132;
    if (sl < 7) {
#pragma unroll
      for (int pp = 0; pp < 16; ++pp) {
        half2_t hp = ash2(Swp[(ylo >> 1) + pp]);
        float e0 = exp2f((float)hp[0] - rowm);
        float e1 = exp2f((float)hp[1] - rowm);
        Swp[(ylo >> 1) + pp] = packh2(e0, e1);
        sacc += e0 + e1;
      }
    } else {
#pragma unroll
      for (int pp = 0; pp < 13; ++pp) {
        half2_t hp = ash2(Swp[112 + pp]);
        float e0 = exp2f((float)hp[0] - rowm);
        float e1 = exp2f((float)hp[1] - rowm);
        Swp[112 + pp] = packh2(e0, e1);
        sacc += e0 + e1;
      }
      float e = exp2f((float)S[xx * 264 + 250] - rowm);
      S[xx * 264 + 250] = (_Float16)e;
      sacc += e;
    }
    sred[sl * 32 + xx] = sacc;
  }
  __syncthreads();
  float denom = 0.f;
#pragma unroll
  for (int s = 0; s < 8; ++s) denom += sred[s * 32 + xx];

  // ---- MFMA PV: C[d][x]; K-split across 4 waves ----
  f32x16_t acc = {};
  int xcol = lane & 31;
  int khh = lane >> 5;
  const _Float16* Srow = S + xcol * 264;
  {
    const unsigned* vhb = vh + (size_t)bbh * 128 * 32 + xcol;
#pragma unroll
    for (int ks = 0; ks < 4; ++ks) {
      int y0 = 64 * wvid + 16 * ks + 8 * khh;
      int t0 = y0 >> 1;
      uint4 au = {vhb[(size_t)(t0 + 0) * 32], vhb[(size_t)(t0 + 1) * 32],
                  vhb[(size_t)(t0 + 2) * 32], vhb[(size_t)(t0 + 3) * 32]};
      half8_t af = __builtin_bit_cast(half8_t, au);
      half8_t bf = *(const half8_t*)(Srow + y0);
      acc = __builtin_amdgcn_mfma_f32_32x32x16_f16(af, bf, acc, 0, 0, 0);
    }
    const unsigned* vpb = vetp + xcol;
    int ybase = xcol + x0 - 250;
#pragma unroll
    for (int ks = 0; ks < 8; ++ks) {
      int p0 = 128 * wvid + 16 * ks + 8 * khh;
      int t0 = p0 >> 1;
      uint4 au = {vpb[(size_t)(t0 + 0) * 32], vpb[(size_t)(t0 + 1) * 32],
                  vpb[(size_t)(t0 + 2) * 32], vpb[(size_t)(t0 + 3) * 32]};
      half8_t af = __builtin_bit_cast(half8_t, au);
      half8_t bf;
#pragma unroll
      for (int e = 0; e < 8; ++e) {
        int yv = ybase + p0 + e;
        bf[e] = ((unsigned)yv < 264u) ? Srow[yv] : (_Float16)0.f;
      }
      acc = __builtin_amdgcn_mfma_f32_32x32x16_f16(af, bf, acc, 0, 0, 0);
    }
  }

  // ---- cross-wave C reduction via Cred (winU space), wave 0 stores ----
  if (wvid > 0) {
    float* cp = Cred + ((size_t)(wvid - 1) * 64 + lane) * 17;
#pragma unroll
    for (int r = 0; r < 16; ++r) cp[r] = acc[r];
  }
  __syncthreads();
  if (wvid == 0) {
#pragma unroll
    for (int w2 = 0; w2 < 3; ++w2) {
      const float* cp = Cred + ((size_t)w2 * 64 + lane) * 17;
#pragma unroll
      for (int r = 0; r < 16; ++r) acc[r] += cp[r];
    }
    if (xcol < nr) {
      float rinv = 1.0f / denom;
      int xg = x0 + xcol;
#pragma unroll
      for (int r = 0; r < 16; ++r) {
        int d = (r & 3) + 8 * (r >> 2) + 4 * khh;
        out[(((size_t)b * 256 + h * 32 + d) * 15 + hi) * WPOS + xg] = acc[r] * rinv;
      }
    }
  }
}

// ---------------- launch ----------------
extern "C" void kernel_launch(void* const* d_in, const int* in_sizes, int n_in,
                              void* d_out, int out_size, void* d_ws, size_t ws_size,
                              hipStream_t stream) {
  const float* x    = (const float*)d_in[0];
  const float* y    = (const float*)d_in[1];
  const float* wk   = (const float*)d_in[2];
  const float* wq   = (const float*)d_in[3];
  const float* wv   = (const float*)d_in[4];
  const float* gk   = (const float*)d_in[5];
  const float* bk   = (const float*)d_in[6];
  const float* gq   = (const float*)d_in[7];
  const float* bq   = (const float*)d_in[8];
  const float* gkq  = (const float*)d_in[9];
  const float* bkq  = (const float*)d_in[10];
  const float* glog = (const float*)d_in[11];
  const float* rel  = (const float*)d_in[13];
  float* out = (float*)d_out;
  float* ws  = (float*)d_ws;

  float* z      = ws + OFF_Z;
  unsigned* vh  = (unsigned*)(ws + OFF_VH);
  unsigned* retc= (unsigned*)(ws + OFF_RETC);
  unsigned* vetp= (unsigned*)(ws + OFF_VETP);
  float* p1q    = ws + OFF_P1Q;
  float* p1k    = ws + OFF_P1K;
  float* p2q    = ws + OFF_P2Q;
  float* p2k    = ws + OFF_P2K;
  float* lpp    = ws + OFF_LPP;
  float* cps    = ws + OFF_CPS;
  float* cps2   = ws + OFF_CPS2;
  float* csum   = ws + OFF_CS;
  float* csum2  = ws + OFF_CS2;
  float* lp     = ws + OFF_LPF;

  k_pre<<<608, 256, 0, stream>>>(rel, retc, vetp, p1q, p1k, p2q, p2k);
  dim3 g1(4, 8, NBB);
  k_gemm<<<g1, 256, 0, stream>>>(x, y, wk, wq, wv, z, cps, cps2);
  k_cred<<<32, 256, 0, stream>>>(cps, cps2, csum, csum2);
  k_mid<<<1920, 256, 0, stream>>>(z, gk, bk, gq, bq, gkq, bkq, csum, csum2,
                                  vh, p1q, p1k, p2q, p2k, lpp);
  k_lstats2<<<240, 256, 0, stream>>>(lpp, lp);
  k_attn<<<240 * 8, 256, 0, stream>>>(z, gk, bk, gq, bq, gkq, bkq, csum, csum2,
                                      vh, retc, vetp, lp, glog, out);
}

// Round 13
// 107.900 us; speedup vs baseline: 1.4818x; 1.0214x over previous
//
#include <hip/hip_runtime.h>
#include <hip/hip_bf16.h>
#include <cstdint>

#define WPOS 251
#define NBB  30
#define NCH  512
#define RELP 501
#define NEPS 1e-5f

typedef _Float16 half2_t __attribute__((ext_vector_type(2)));
typedef _Float16 half8_t __attribute__((ext_vector_type(8)));
typedef float f32x16_t __attribute__((ext_vector_type(16)));

#if defined(__has_builtin)
#if __has_builtin(__builtin_amdgcn_fdot2)
#define FDOT2(a, b, c) __builtin_amdgcn_fdot2((a), (b), (c), false)
#endif
#endif
#ifndef FDOT2
#define FDOT2(a, b, c) ((float)(a)[0] * (float)(b)[0] + (float)(a)[1] * (float)(b)[1] + (c))
#endif

// ---------------- workspace layout (in float slots) ----------------
static constexpr size_t SZ_Z     = (size_t)NBB * NCH * WPOS;
static constexpr size_t OFF_Z    = 0;
static constexpr size_t OFF_VH   = OFF_Z + SZ_Z;                   // uint[bbh][128][32] half2 v pairs
static constexpr size_t SZ_VH    = (size_t)NBB * 8 * 128 * 32;
static constexpr size_t OFF_RETC = OFF_VH + SZ_VH;                 // uint[501][16]: qe|keR fp16 pairs
static constexpr size_t OFF_VETP = OFF_RETC + (size_t)RELP * 16;   // uint[256][32] half2 p-pairs
static constexpr size_t OFF_P1Q  = OFF_VETP + (size_t)256 * 32;    // [16][502]
static constexpr size_t OFF_P1K  = OFF_P1Q + (size_t)16 * 502;
static constexpr size_t OFF_P2Q  = OFF_P1K + (size_t)16 * 502;     // [256][502]
static constexpr size_t OFF_P2K  = OFF_P2Q + (size_t)256 * 502;
static constexpr size_t OFF_LPP  = OFF_P2K + (size_t)256 * 502;    // [960][548] partials
static constexpr size_t OFF_CPS  = OFF_LPP + (size_t)960 * 548;    // [240][512] channel sum partials
static constexpr size_t OFF_CPS2 = OFF_CPS + (size_t)240 * 512;    // [240][512]
static constexpr size_t OFF_CS   = OFF_CPS2 + (size_t)240 * 512;   // csum[512]
static constexpr size_t OFF_CS2  = OFF_CS + 512;                   // csum2[512]
static constexpr size_t OFF_LPF  = OFF_CS2 + 512;                  // lp[240][6]

static __device__ __forceinline__ unsigned packh2(float a, float b) {
  half2_t t;
  t[0] = (_Float16)a;
  t[1] = (_Float16)b;
  return __builtin_bit_cast(unsigned, t);
}
static __device__ __forceinline__ half2_t ash2(unsigned u) {
  return __builtin_bit_cast(half2_t, u);
}

// ---------------- K0: rel prep (64 blocks) + prefix scans (544 blocks) ----------------
__global__ __launch_bounds__(256) void k_pre(
    const float* __restrict__ rel, unsigned* __restrict__ retc, unsigned* __restrict__ vetp,
    float* __restrict__ p1q, float* __restrict__ p1k,
    float* __restrict__ p2q, float* __restrict__ p2k) {
  int blk = blockIdx.x;
  if (blk < 64) {
    int idx = blk * 256 + threadIdx.x;
    if (idx < RELP * 16) {
      int p = idx >> 4, j = idx & 15;
      float lo, hi;
      if (j < 8) {
        lo = rel[(size_t)(2 * j) * RELP + p];
        hi = rel[(size_t)(2 * j + 1) * RELP + p];
      } else {
        int jj = j - 8;
        lo = rel[(size_t)(16 + 2 * jj) * RELP + (500 - p)];
        hi = rel[(size_t)(17 + 2 * jj) * RELP + (500 - p)];
      }
      retc[(size_t)p * 16 + j] = packh2(lo, hi);
    } else if (idx < RELP * 16 + 256 * 32) {
      int i2 = idx - RELP * 16;
      int t = i2 >> 5, ch = i2 & 31;
      float lo = (2 * t <= 500) ? rel[(size_t)(32 + ch) * RELP + 2 * t] : 0.f;
      float hi = (2 * t + 1 <= 500) ? rel[(size_t)(32 + ch) * RELP + 2 * t + 1] : 0.f;
      vetp[(size_t)t * 32 + ch] = packh2(lo, hi);
    }
    return;
  }
  int task = blk - 64;   // 0..543
  const float* ra;
  const float* rb = nullptr;
  float* outp;
  if (task < 16)        { ra = rel + (size_t)task * RELP; outp = p1q + (size_t)task * 502; }
  else if (task < 32)   { ra = rel + (size_t)task * RELP; outp = p1k + (size_t)(task - 16) * 502; }
  else if (task < 288)  { int pr = task - 32;
                          ra = rel + (size_t)(pr >> 4) * RELP;
                          rb = rel + (size_t)(pr & 15) * RELP;
                          outp = p2q + (size_t)pr * 502; }
  else                  { int pr = task - 288;
                          ra = rel + (size_t)(16 + (pr >> 4)) * RELP;
                          rb = rel + (size_t)(16 + (pr & 15)) * RELP;
                          outp = p2k + (size_t)pr * 502; }
  __shared__ float buf[256];
  int t = threadIdx.x;
  int i0 = 2 * t, i1 = 2 * t + 1;
  float a0 = (i0 < RELP) ? (rb ? ra[i0] * rb[i0] : ra[i0]) : 0.f;
  float a1 = (i1 < RELP) ? (rb ? ra[i1] * rb[i1] : ra[i1]) : 0.f;
  buf[t] = a0 + a1;
  __syncthreads();
#pragma unroll
  for (int off = 1; off < 256; off <<= 1) {
    float v = buf[t];
    float add = (t >= off) ? buf[t - off] : 0.f;
    __syncthreads();
    buf[t] = v + add;
    __syncthreads();
  }
  float ex = buf[t] - (a0 + a1);
  if (i0 <= RELP) outp[i0] = ex;
  if (i1 <= RELP) outp[i1] = ex + a0;
}

// ---------------- K1: kqv GEMM via fp16 MFMA + contention-free stat partials ----------------
__global__ __launch_bounds__(256) void k_gemm(
    const float* __restrict__ x, const float* __restrict__ y,
    const float* __restrict__ wk, const float* __restrict__ wq,
    const float* __restrict__ wv, float* __restrict__ z,
    float* __restrict__ cps, float* __restrict__ cps2) {
  int l0 = blockIdx.x * 64;
  int o0 = blockIdx.y * 64;
  int bb = blockIdx.z;
  int b = bb / 15, hi = bb % 15;
  const float* src;
  const float* wmat;
  int orow0;
  if (o0 < 128)      { wmat = wk; orow0 = o0;       src = x; }
  else if (o0 < 256) { wmat = wq; orow0 = o0 - 128; src = y; }
  else               { wmat = wv; orow0 = o0 - 256; src = x; }

  __shared__ _Float16 Ah[64][68];   // [o][k]
  __shared__ _Float16 Bh[64][68];   // [k][l]

  int tid = threadIdx.x;
  int lane = tid & 63, wv4 = tid >> 6;
  int wo = wv4 >> 1, wl = wv4 & 1;
  int m = lane & 31, kh = lane >> 5;

  f32x16_t acc = {};

  int cA = tid & 63, ogA = tid >> 6;
  int lB = tid & 63, kgB = tid >> 6;
  int lglob = l0 + lB;
  bool lok = (lglob < WPOS);
  const float* xcol = src + (size_t)(((size_t)b * 256) * 15 + hi) * WPOS + lglob;

  for (int c0 = 0; c0 < 256; c0 += 64) {
#pragma unroll
    for (int i = 0; i < 16; ++i) {
      int o = ogA * 16 + i;
      Ah[o][cA] = (_Float16)wmat[(size_t)(orow0 + o) * 256 + c0 + cA];
    }
#pragma unroll
    for (int i = 0; i < 16; ++i) {
      int k = kgB * 16 + i;
      float v = lok ? xcol[(size_t)(c0 + k) * 15 * WPOS] : 0.f;
      Bh[k][lB] = (_Float16)v;
    }
    __syncthreads();
#pragma unroll
    for (int ks = 0; ks < 4; ++ks) {
      const _Float16* ap = &Ah[wo * 32 + m][ks * 16 + kh * 8];
      uint2 aLo = *(const uint2*)(ap);
      uint2 aHi = *(const uint2*)(ap + 4);
      uint4 au = {aLo.x, aLo.y, aHi.x, aHi.y};
      half8_t af = __builtin_bit_cast(half8_t, au);
      half8_t bf;
      int kb = ks * 16 + kh * 8;
      int bcol = wl * 32 + m;
#pragma unroll
      for (int e = 0; e < 8; ++e) bf[e] = Bh[kb + e][bcol];
      acc = __builtin_amdgcn_mfma_f32_32x32x16_f16(af, bf, acc, 0, 0, 0);
    }
    __syncthreads();
  }

  int n = lane & 31;
  int lout = l0 + wl * 32 + n;
  if (lout < WPOS) {
#pragma unroll
    for (int r = 0; r < 16; ++r) {
      int mrow = (r & 3) + 8 * (r >> 2) + 4 * kh;
      int o = o0 + wo * 32 + mrow;
      z[((size_t)bb * NCH + o) * WPOS + lout] = acc[r];
    }
  }

  // ---- channel partial sums: single writer per (part, o) -> no atomics ----
  int part = (blockIdx.x * 2 + wl) * NBB + bb;
#pragma unroll
  for (int r = 0; r < 16; ++r) {
    float s = acc[r];
    float s2 = s * s;
#pragma unroll
    for (int m2 = 1; m2 < 32; m2 <<= 1) {
      s  += __shfl_xor(s, m2, 64);
      s2 += __shfl_xor(s2, m2, 64);
    }
    if (n == 0) {
      int mrow = (r & 3) + 8 * (r >> 2) + 4 * kh;
      int o = o0 + wo * 32 + mrow;
      cps[(size_t)part * 512 + o] = s;
      cps2[(size_t)part * 512 + o] = s2;
    }
  }
}

// ---------------- K1b: reduce 240 channel partials -> csum/csum2 ----------------
__global__ __launch_bounds__(256) void k_cred(
    const float* __restrict__ cps, const float* __restrict__ cps2,
    float* __restrict__ csum, float* __restrict__ csum2) {
  int c = blockIdx.x * 16 + (threadIdx.x & 15);
  int grp = threadIdx.x >> 4;           // 16 groups x 15 parts = 240
  __shared__ float r1[256], r2[256];
  float s = 0.f, s2 = 0.f;
  for (int i = 0; i < 15; ++i) {
    int p = grp * 15 + i;
    s += cps[(size_t)p * 512 + c];
    s2 += cps2[(size_t)p * 512 + c];
  }
  r1[threadIdx.x] = s; r2[threadIdx.x] = s2;
  __syncthreads();
  for (int st = 128; st >= 16; st >>= 1) {
    if (threadIdx.x < st) {
      r1[threadIdx.x] += r1[threadIdx.x + st];
      r2[threadIdx.x] += r2[threadIdx.x + st];
    }
    __syncthreads();
  }
  if (threadIdx.x < 16) {
    csum[c] = r1[threadIdx.x];
    csum2[c] = r2[threadIdx.x];
  }
}

// ---------------- helpers ----------------
__device__ __forceinline__ float block_reduce(float v, float* red, int tid) {
  red[tid] = v; __syncthreads();
  for (int s = 128; s > 0; s >>= 1) {
    if (tid < s) red[tid] += red[tid + s];
    __syncthreads();
  }
  float r = red[0]; __syncthreads();
  return r;
}

__device__ __forceinline__ void chan_affine(
    int ch, const float* gk, const float* bk, const float* gq, const float* bq,
    const float* gkq, const float* bkq, const float* csum, const float* csum2,
    float& a, float& bout) {
  float g, bi;
  if (ch < 128)      { g = gk[ch];        bi = bk[ch]; }
  else if (ch < 256) { g = gq[ch - 128];  bi = bq[ch - 128]; }
  else               { g = gkq[ch - 256]; bi = bkq[ch - 256]; }
  float n = (float)(NBB * WPOS);
  float mean = csum[ch] / n;
  float var = csum2[ch] / n - mean * mean;
  a = g / sqrtf(var + NEPS);
  bout = bi - mean * a;
}

// ---------------- K2: merged norm_vh (blocks 0..959) + lstats1 (960..1919) ----------------
__global__ __launch_bounds__(256) void k_mid(
    const float* __restrict__ z,
    const float* __restrict__ gk, const float* __restrict__ bk,
    const float* __restrict__ gq, const float* __restrict__ bq,
    const float* __restrict__ gkq, const float* __restrict__ bkq,
    const float* __restrict__ csum, const float* __restrict__ csum2,
    unsigned* __restrict__ vh,
    const float* __restrict__ p1q, const float* __restrict__ p1k,
    const float* __restrict__ p2q, const float* __restrict__ p2k,
    float* __restrict__ lpp) {
  int blk = blockIdx.x;
  bool isV = (blk < 960);
  int sblk = isV ? blk : blk - 960;
  int bbh = sblk % 240, sub = sblk / 240;
  int bb = bbh >> 3, h = bbh & 7;
  int tid = threadIdx.x;

  __shared__ __align__(16) float pool[16 * 68 * 2];
  __shared__ float red[256];
  __shared__ float caL[32], cbL[32];
  __shared__ int pairLUT[136];

  if (tid < 32) {
    int ch = h * 64 + (isV ? 32 + tid : tid);
    chan_affine(ch, gk, bk, gq, bq, gkq, bkq, csum, csum2, caL[tid], cbL[tid]);
  } else if (tid >= 64 && tid < 200) {
    int i = tid - 64, rem = i, d = 0;
    while (rem >= 16 - d) { rem -= 16 - d; ++d; }
    pairLUT[i] = (d << 4) | (d + rem);
  }
  __syncthreads();

  if (isV) {
    float (*T)[65] = (float(*)[65])pool;
    int l0 = sub * 64;
    const float* zv = z + ((size_t)bb * NCH + h * 64 + 32) * WPOS;
    for (int i = tid; i < 32 * 64; i += 256) {
      int ch = i >> 6, l = i & 63;
      int gl = l0 + l;
      T[ch][l] = (gl < WPOS) ? (caL[ch] * zv[(size_t)ch * WPOS + gl] + cbL[ch]) : 0.f;
    }
    __syncthreads();
    int p0 = l0 >> 1;
    for (int i = tid; i < 32 * 32; i += 256) {
      int pl = i >> 5, ch = i & 31;
      int gp = p0 + pl;
      if (gp < 128)
        vh[((size_t)bbh * 128 + gp) * 32 + ch] = packh2(T[ch][2 * pl], T[ch][2 * pl + 1]);
    }
    return;
  }

  float (*qs)[68] = (float(*)[68])pool;
  float (*ks)[68] = (float(*)[68])(pool + 16 * 68);
  int x0 = sub * 64;
  const float* zb = z + ((size_t)bb * NCH + h * 64) * WPOS;
  for (int idx = tid; idx < 16 * 64; idx += 256) {
    int d = idx >> 6, xl = idx & 63;
    int xg = x0 + xl;
    float kv = 0.f, qv = 0.f;
    if (xg < WPOS) {
      kv = caL[d] * zb[(size_t)d * WPOS + xg] + cbL[d];
      qv = caL[16 + d] * zb[(size_t)(16 + d) * WPOS + xg] + cbL[16 + d];
    }
    ks[d][xl] = kv; qs[d][xl] = qv;
  }
  __syncthreads();
  float* outp = lpp + ((size_t)bbh * 4 + sub) * 548;
  if (tid < 16) {
    float s = 0.f;
    for (int xl = 0; xl < 64; ++xl) s += qs[tid][xl];
    outp[516 + tid] = s;
  } else if (tid < 32) {
    float s = 0.f;
    for (int xl = 0; xl < 64; ++xl) s += ks[tid - 16][xl];
    outp[532 + (tid - 16)] = s;
  }
  {
    int d = tid >> 4, d2 = tid & 15;
    float g1 = 0.f, g2 = 0.f;
    for (int xl = 0; xl < 64; ++xl) {
      g1 += qs[d][xl] * qs[d2][xl];
      g2 += ks[d][xl] * ks[d2][xl];
    }
    outp[tid] = g1;
    outp[256 + tid] = g2;
  }
  // ---- band terms: symmetric-halved (136 pairs), lane = xl (coalesced) ----
  float v_sumqr = 0.f, v_sqqr = 0.f, v_sumkr = 0.f, v_sqkr = 0.f;
  {
    int xl = tid & 63, wv = tid >> 6;
    int xg = x0 + xl;
    if (xg < WPOS) {
      int ihi = 501 - xg, ilo = 250 - xg;
      for (int i = wv; i < 136; i += 4) {
        int pc = pairLUT[i];
        int d = pc >> 4, d2 = pc & 15;
        float wgt = (d == d2) ? 1.f : 2.f;
        const float* pq = p2q + (size_t)(d * 16 + d2) * 502;
        const float* pk = p2k + (size_t)(d * 16 + d2) * 502;
        v_sqqr += wgt * qs[d][xl] * qs[d2][xl] * (pq[ihi] - pq[ilo]);
        v_sqkr += wgt * ks[d][xl] * ks[d2][xl] * (pk[ihi] - pk[ilo]);
      }
      for (int d = wv; d < 16; d += 4) {
        v_sumqr += qs[d][xl] * (p1q[d * 502 + ihi] - p1q[d * 502 + ilo]);
        v_sumkr += ks[d][xl] * (p1k[d * 502 + ihi] - p1k[d * 502 + ilo]);
      }
    }
  }
  float r1 = block_reduce(v_sumqr, red, tid);
  float r2 = block_reduce(v_sqqr, red, tid);
  float r3 = block_reduce(v_sumkr, red, tid);
  float r4 = block_reduce(v_sqkr, red, tid);
  if (tid == 0) { outp[512] = r1; outp[513] = r2; outp[514] = r3; outp[515] = r4; }
}

// ---------------- K3: combine partials -> lp[bbh][6] (plain writes) ----------------
__global__ __launch_bounds__(256) void k_lstats2(const float* __restrict__ lpp,
                                                 float* __restrict__ lp) {
  int bbh = blockIdx.x;
  int tid = threadIdx.x;
  __shared__ float red[256];
  __shared__ float qsums[16], ksums[16];
  const float* b0 = lpp + (size_t)bbh * 4 * 548;
  float qg = b0[tid] + b0[548 + tid] + b0[1096 + tid] + b0[1644 + tid];
  float kg = b0[256 + tid] + b0[804 + tid] + b0[1352 + tid] + b0[1900 + tid];
  if (tid < 16) {
    qsums[tid] = b0[516 + tid] + b0[1064 + tid] + b0[1612 + tid] + b0[2160 + tid];
    ksums[tid] = b0[532 + tid] + b0[1080 + tid] + b0[1628 + tid] + b0[2176 + tid];
  }
  float sqqk = block_reduce(qg * kg, red, tid);
  if (tid == 0) {
    float sum_qk = 0.f;
    for (int d = 0; d < 16; ++d) sum_qk += qsums[d] * ksums[d];
    float s1 = 0.f, s2 = 0.f, s3 = 0.f, s4 = 0.f;
    for (int c = 0; c < 4; ++c) {
      const float* bc = b0 + (size_t)c * 548;
      s1 += bc[512]; s2 += bc[513]; s3 += bc[514]; s4 += bc[515];
    }
    float* o = lp + (size_t)bbh * 6;
    o[0] = sum_qk; o[1] = sqqk;
    o[2] = s1; o[3] = s2; o[4] = s3; o[5] = s4;
  }
}

// ---------------- K4: fused logits + softmax + MFMA attention ----------------
__global__ __launch_bounds__(256) void k_attn(
    const float* __restrict__ z,
    const float* __restrict__ gk, const float* __restrict__ bk,
    const float* __restrict__ gq, const float* __restrict__ bq,
    const float* __restrict__ gkq, const float* __restrict__ bkq,
    const float* __restrict__ csum, const float* __restrict__ csum2,
    const unsigned* __restrict__ vh,
    const unsigned* __restrict__ retc, const unsigned* __restrict__ vetp,
    const float* __restrict__ lp, const float* __restrict__ glog,
    float* __restrict__ out) {
  int blk = blockIdx.x;
  int bbh = blk % 240, tile = blk / 240;
  int bb = bbh >> 3, h = bbh & 7;
  int b = bb / 15, hi = bb % 15;
  int x0 = tile * 32;
  int nr = min(32, WPOS - x0);
  int tid = threadIdx.x;
  int lane = tid & 63, wvid = tid >> 6;

  const float LOG2E = 1.4426950408889634f;

  __shared__ __align__(16) unsigned Su[32 * 132];     // fp16 S, 264 halfs/row
  __shared__ __align__(16) unsigned winU[282 * 18];   // rel rows; later Cred
  __shared__ __align__(16) unsigned uSh[256];
  __shared__ float affL[72];                          // ca[32] cb[32] lsums[6]
  _Float16* S = (_Float16*)Su;
  unsigned* qsP = uSh;
  float* sred = (float*)uSh;
  float* Cred = (float*)winU;

  int pwin0 = 251 - x0 - nr;
  int nwin = 250 + nr;

  // ---- inline channel affine + logit stat sums over bb ----
  if (tid < 32) {
    int ch = h * 64 + tid;
    chan_affine(ch, gk, bk, gq, bq, gkq, bkq, csum, csum2, affL[tid], affL[32 + tid]);
  } else if (tid >= 64 && tid < 70) {
    int grp = (tid - 64) >> 1, off = (tid - 64) & 1;
    float s = 0.f;
    for (int bb2 = 0; bb2 < NBB; ++bb2)
      s += lp[(size_t)(bb2 * 8 + h) * 6 + grp * 2 + off];
    affL[64 + (tid - 64)] = s;
  }
  __syncthreads();
  float la_qk, la_qr, la_kr;
  {
    float n = (float)NBB * (float)WPOS * (float)WPOS;
    float m0 = affL[64] / n, v0 = affL[65] / n - m0 * m0;
    float m1 = affL[66] / n, v1 = affL[67] / n - m1 * m1;
    float m2 = affL[68] / n, v2 = affL[69] / n - m2 * m2;
    la_qk = glog[0 * 8 + h] / sqrtf(v0 + NEPS) * LOG2E;
    la_qr = glog[1 * 8 + h] / sqrtf(v1 + NEPS) * LOG2E;
    la_kr = glog[2 * 8 + h] / sqrtf(v2 + NEPS) * LOG2E;
  }

  const float* zb = z + ((size_t)bb * NCH + h * 64) * WPOS;

  // ---- stage rel window into LDS ----
  for (int i = tid; i < nwin * 16; i += 256) {
    int r = i >> 4, j = i & 15;
    winU[r * 18 + j] = retc[(size_t)(pwin0 + r) * 16 + j];
  }

  // ---- stage q tile (affine from raw z, fp16-packed) ----
  {
    int xx = tid & 31, j = tid >> 5;
    int xcl = min(x0 + xx, WPOS - 1);
    float q0 = affL[16 + 2 * j] * zb[(size_t)(16 + 2 * j) * WPOS + xcl] + affL[48 + 2 * j];
    float q1 = affL[17 + 2 * j] * zb[(size_t)(17 + 2 * j) * WPOS + xcl] + affL[49 + 2 * j];
    qsP[xx * 8 + j] = packh2(q0, q1);
  }

  // ---- k row per lane (affine from raw z), fp16-packed ----
  int yy = wvid * 64 + lane;
  int yc = min(yy, WPOS - 1);
  bool yok = (yy < WPOS);
  half2_t khv[8];
#pragma unroll
  for (int d = 0; d < 8; ++d) {
    float k0 = affL[2 * d]     * zb[(size_t)(2 * d) * WPOS + yc] + affL[32 + 2 * d];
    float k1 = affL[2 * d + 1] * zb[(size_t)(2 * d + 1) * WPOS + yc] + affL[33 + 2 * d];
    khv[d] = __builtin_bit_cast(half2_t, packh2(k0, k1));
  }
  __syncthreads();

  // ---- fused S: qk + qr + kr, log2 domain; lanes on y, loop over x ----
  {
    int rowbase = yc + nr - 1;
    for (int xx = 0; xx < nr; ++xx) {
      const unsigned* wr = &winU[(size_t)(rowbase - xx) * 18];
      const unsigned* qp = &qsP[xx * 8];
      float dqk = 0.f, dqr = 0.f, dkr = 0.f;
#pragma unroll
      for (int j2 = 0; j2 < 4; ++j2) {
        uint2 ue = *(const uint2*)(wr + 2 * j2);
        uint2 uk = *(const uint2*)(wr + 8 + 2 * j2);
        uint2 uq = *(const uint2*)(qp + 2 * j2);
        half2_t qe0 = ash2(ue.x), qe1 = ash2(ue.y);
        half2_t ke0 = ash2(uk.x), ke1 = ash2(uk.y);
        half2_t q0  = ash2(uq.x), q1  = ash2(uq.y);
        half2_t k0 = khv[2 * j2], k1 = khv[2 * j2 + 1];
        dqk = FDOT2(q0, k0, dqk);  dqk = FDOT2(q1, k1, dqk);
        dqr = FDOT2(q0, qe0, dqr); dqr = FDOT2(q1, qe1, dqr);
        dkr = FDOT2(k0, ke0, dkr); dkr = FDOT2(k1, ke1, dkr);
      }
      float sval = la_qk * dqk + la_qr * dqr + la_kr * dkr;
      S[xx * 264 + yy] = yok ? (_Float16)sval : (_Float16)0.f;
    }
  }
  // ---- zero pad: cols 256..263; full rows nr..31 (tile 7) ----
  for (int i = tid; i < 32 * 8; i += 256)
    S[(i >> 3) * 264 + 256 + (i & 7)] = (_Float16)0.f;
  if (nr < 32) {
    int ntail = (32 - nr) * 264;
    for (int i = tid; i < ntail; i += 256) S[nr * 264 + i] = (_Float16)0.f;
  }
  __syncthreads();

  // ---- softmax over y; lanes on x, 8 slices; pair-wise fp16 ----
  int xx = lane & 31;
  int sl = wvid * 2 + (lane >> 5);
  int ylo = sl * 32;
  const unsigned* Srp = Su + xx * 132;
  {
    float m = -1e30f;
    if (sl < 7) {
#pragma unroll
      for (int pp = 0; pp < 16; ++pp) {
        half2_t hp = ash2(Srp[(ylo >> 1) + pp]);
        m = fmaxf(m, fmaxf((float)hp[0], (float)hp[1]));
      }
    } else {
#pragma unroll
      for (int pp = 0; pp < 13; ++pp) {
        half2_t hp = ash2(Srp[112 + pp]);
        m = fmaxf(m, fmaxf((float)hp[0], (float)hp[1]));
      }
      m = fmaxf(m, (float)S[xx * 264 + 250]);
    }
    sred[sl * 32 + xx] = m;
  }
  __syncthreads();
  float rowm = sred[0 * 32 + xx];
#pragma unroll
  for (int s = 1; s < 8; ++s) rowm = fmaxf(rowm, sred[s * 32 + xx]);
  __syncthreads();
  {
    float sacc = 0.f;
    unsigned* Swp = Su + xx * 132;
    if (sl < 7) {
#pragma unroll
      for (int pp = 0; pp < 16; ++pp) {
        half2_t hp = ash2(Swp[(ylo >> 1) + pp]);
        float e0 = exp2f((float)hp[0] - rowm);
        float e1 = exp2f((float)hp[1] - rowm);
        Swp[(ylo >> 1) + pp] = packh2(e0, e1);
        sacc += e0 + e1;
      }
    } else {
#pragma unroll
      for (int pp = 0; pp < 13; ++pp) {
        half2_t hp = ash2(Swp[112 + pp]);
        float e0 = exp2f((float)hp[0] - rowm);
        float e1 = exp2f((float)hp[1] - rowm);
        Swp[112 + pp] = packh2(e0, e1);
        sacc += e0 + e1;
      }
      float e = exp2f((float)S[xx * 264 + 250] - rowm);
      S[xx * 264 + 250] = (_Float16)e;
      sacc += e;
    }
    sred[sl * 32 + xx] = sacc;
  }
  __syncthreads();
  float denom = 0.f;
#pragma unroll
  for (int s = 0; s < 8; ++s) denom += sred[s * 32 + xx];

  // ---- MFMA PV: C[d][x]; K-split across 4 waves ----
  f32x16_t acc = {};
  int xcol = lane & 31;
  int khh = lane >> 5;
  const _Float16* Srow = S + xcol * 264;
  {
    const unsigned* vhb = vh + (size_t)bbh * 128 * 32 + xcol;
#pragma unroll
    for (int ks = 0; ks < 4; ++ks) {
      int y0 = 64 * wvid + 16 * ks + 8 * khh;
      int t0 = y0 >> 1;
      uint4 au = {vhb[(size_t)(t0 + 0) * 32], vhb[(size_t)(t0 + 1) * 32],
                  vhb[(size_t)(t0 + 2) * 32], vhb[(size_t)(t0 + 3) * 32]};
      half8_t af = __builtin_bit_cast(half8_t, au);
      half8_t bf = *(const half8_t*)(Srow + y0);
      acc = __builtin_amdgcn_mfma_f32_32x32x16_f16(af, bf, acc, 0, 0, 0);
    }
    const unsigned* vpb = vetp + xcol;
    int ybase = xcol + x0 - 250;
#pragma unroll
    for (int ks = 0; ks < 8; ++ks) {
      int p0 = 128 * wvid + 16 * ks + 8 * khh;
      int t0 = p0 >> 1;
      uint4 au = {vpb[(size_t)(t0 + 0) * 32], vpb[(size_t)(t0 + 1) * 32],
                  vpb[(size_t)(t0 + 2) * 32], vpb[(size_t)(t0 + 3) * 32]};
      half8_t af = __builtin_bit_cast(half8_t, au);
      half8_t bf;
#pragma unroll
      for (int e = 0; e < 8; ++e) {
        int yv = ybase + p0 + e;
        bf[e] = ((unsigned)yv < 264u) ? Srow[yv] : (_Float16)0.f;
      }
      acc = __builtin_amdgcn_mfma_f32_32x32x16_f16(af, bf, acc, 0, 0, 0);
    }
  }

  // ---- cross-wave C reduction via Cred (winU space), wave 0 stores ----
  if (wvid > 0) {
    float* cp = Cred + ((size_t)(wvid - 1) * 64 + lane) * 17;
#pragma unroll
    for (int r = 0; r < 16; ++r) cp[r] = acc[r];
  }
  __syncthreads();
  if (wvid == 0) {
#pragma unroll
    for (int w2 = 0; w2 < 3; ++w2) {
      const float* cp = Cred + ((size_t)w2 * 64 + lane) * 17;
#pragma unroll
      for (int r = 0; r < 16; ++r) acc[r] += cp[r];
    }
    if (xcol < nr) {
      float rinv = 1.0f / denom;
      int xg = x0 + xcol;
#pragma unroll
      for (int r = 0; r < 16; ++r) {
        int d = (r & 3) + 8 * (r >> 2) + 4 * khh;
        out[(((size_t)b * 256 + h * 32 + d) * 15 + hi) * WPOS + xg] = acc[r] * rinv;
      }
    }
  }
}

// ---------------- launch ----------------
extern "C" void kernel_launch(void* const* d_in, const int* in_sizes, int n_in,
                              void* d_out, int out_size, void* d_ws, size_t ws_size,
                              hipStream_t stream) {
  const float* x    = (const float*)d_in[0];
  const float* y    = (const float*)d_in[1];
  const float* wk   = (const float*)d_in[2];
  const float* wq   = (const float*)d_in[3];
  const float* wv   = (const float*)d_in[4];
  const float* gk   = (const float*)d_in[5];
  const float* bk   = (const float*)d_in[6];
  const float* gq   = (const float*)d_in[7];
  const float* bq   = (const float*)d_in[8];
  const float* gkq  = (const float*)d_in[9];
  const float* bkq  = (const float*)d_in[10];
  const float* glog = (const float*)d_in[11];
  const float* rel  = (const float*)d_in[13];
  float* out = (float*)d_out;
  float* ws  = (float*)d_ws;

  float* z      = ws + OFF_Z;
  unsigned* vh  = (unsigned*)(ws + OFF_VH);
  unsigned* retc= (unsigned*)(ws + OFF_RETC);
  unsigned* vetp= (unsigned*)(ws + OFF_VETP);
  float* p1q    = ws + OFF_P1Q;
  float* p1k    = ws + OFF_P1K;
  float* p2q    = ws + OFF_P2Q;
  float* p2k    = ws + OFF_P2K;
  float* lpp    = ws + OFF_LPP;
  float* cps    = ws + OFF_CPS;
  float* cps2   = ws + OFF_CPS2;
  float* csum   = ws + OFF_CS;
  float* csum2  = ws + OFF_CS2;
  float* lp     = ws + OFF_LPF;

  k_pre<<<608, 256, 0, stream>>>(rel, retc, vetp, p1q, p1k, p2q, p2k);
  dim3 g1(4, 8, NBB);
  k_gemm<<<g1, 256, 0, stream>>>(x, y, wk, wq, wv, z, cps, cps2);
  k_cred<<<32, 256, 0, stream>>>(cps, cps2, csum, csum2);
  k_mid<<<1920, 256, 0, stream>>>(z, gk, bk, gq, bq, gkq, bkq, csum, csum2,
                                  vh, p1q, p1k, p2q, p2k, lpp);
  k_lstats2<<<240, 256, 0, stream>>>(lpp, lp);
  k_attn<<<240 * 8, 256, 0, stream>>>(z, gk, bk, gq, bq, gkq, bkq, csum, csum2,
                                      vh, retc, vetp, lp, glog, out);
}

// Round 14
// 100.740 us; speedup vs baseline: 1.5871x; 1.0711x over previous
//
#include <hip/hip_runtime.h>
#include <hip/hip_bf16.h>
#include <cstdint>

#define WPOS 251
#define NBB  30
#define NCH  512
#define RELP 501
#define NEPS 1e-5f

typedef _Float16 half2_t __attribute__((ext_vector_type(2)));
typedef _Float16 half8_t __attribute__((ext_vector_type(8)));
typedef float f32x16_t __attribute__((ext_vector_type(16)));

#if defined(__has_builtin)
#if __has_builtin(__builtin_amdgcn_fdot2)
#define FDOT2(a, b, c) __builtin_amdgcn_fdot2((a), (b), (c), false)
#endif
#endif
#ifndef FDOT2
#define FDOT2(a, b, c) ((float)(a)[0] * (float)(b)[0] + (float)(a)[1] * (float)(b)[1] + (c))
#endif

// ---------------- workspace layout (in float slots) ----------------
static constexpr size_t SZ_Z     = (size_t)NBB * NCH * WPOS;
static constexpr size_t OFF_Z    = 0;
static constexpr size_t OFF_VH   = OFF_Z + SZ_Z;                   // uint[bbh][128][32] half2 v pairs
static constexpr size_t SZ_VH    = (size_t)NBB * 8 * 128 * 32;
static constexpr size_t OFF_RETC = OFF_VH + SZ_VH;                 // uint[501][16]: qe|keR fp16 pairs
static constexpr size_t OFF_VETP = OFF_RETC + (size_t)RELP * 16;   // uint[256][32] half2 p-pairs
static constexpr size_t OFF_D1Q  = OFF_VETP + (size_t)256 * 32;    // [16][256] window diffs
static constexpr size_t OFF_D1K  = OFF_D1Q + (size_t)16 * 256;
static constexpr size_t OFF_D2Q  = OFF_D1K + (size_t)16 * 256;     // [136][256]
static constexpr size_t OFF_D2K  = OFF_D2Q + (size_t)136 * 256;
static constexpr size_t OFF_LPP  = OFF_D2K + (size_t)136 * 256;    // [960][548] partials
static constexpr size_t OFF_CPS  = OFF_LPP + (size_t)960 * 548;    // [240][512] channel sum partials
static constexpr size_t OFF_CPS2 = OFF_CPS + (size_t)240 * 512;    // [240][512]
static constexpr size_t OFF_CS   = OFF_CPS2 + (size_t)240 * 512;   // csum[512]
static constexpr size_t OFF_CS2  = OFF_CS + 512;                   // csum2[512]
static constexpr size_t OFF_LPF  = OFF_CS2 + 512;                  // lp[240][6]

static __device__ __forceinline__ unsigned packh2(float a, float b) {
  half2_t t;
  t[0] = (_Float16)a;
  t[1] = (_Float16)b;
  return __builtin_bit_cast(unsigned, t);
}
static __device__ __forceinline__ half2_t ash2(unsigned u) {
  return __builtin_bit_cast(half2_t, u);
}

// ---------------- K1: fused {rel prep | scans+diffs | kqv MFMA GEMM} ----------------
// blocks [0,64): rel prep; [64,368): 304 scan tasks -> D tables; [368,1328): GEMM.
__global__ __launch_bounds__(256) void k_gemm_pre(
    const float* __restrict__ x, const float* __restrict__ y,
    const float* __restrict__ wk, const float* __restrict__ wq,
    const float* __restrict__ wv, const float* __restrict__ rel,
    float* __restrict__ z, float* __restrict__ cps, float* __restrict__ cps2,
    unsigned* __restrict__ retc, unsigned* __restrict__ vetp,
    float* __restrict__ d1q, float* __restrict__ d1k,
    float* __restrict__ d2q, float* __restrict__ d2k) {
  int blk = blockIdx.x;
  int tid = threadIdx.x;

  if (blk < 64) {   // ---- rel prep ----
    int idx = blk * 256 + tid;
    if (idx < RELP * 16) {
      int p = idx >> 4, j = idx & 15;
      float lo, hi;
      if (j < 8) {
        lo = rel[(size_t)(2 * j) * RELP + p];
        hi = rel[(size_t)(2 * j + 1) * RELP + p];
      } else {
        int jj = j - 8;
        lo = rel[(size_t)(16 + 2 * jj) * RELP + (500 - p)];
        hi = rel[(size_t)(17 + 2 * jj) * RELP + (500 - p)];
      }
      retc[(size_t)p * 16 + j] = packh2(lo, hi);
    } else if (idx < RELP * 16 + 256 * 32) {
      int i2 = idx - RELP * 16;
      int t = i2 >> 5, ch = i2 & 31;
      float lo = (2 * t <= 500) ? rel[(size_t)(32 + ch) * RELP + 2 * t] : 0.f;
      float hi = (2 * t + 1 <= 500) ? rel[(size_t)(32 + ch) * RELP + 2 * t + 1] : 0.f;
      vetp[(size_t)t * 32 + ch] = packh2(lo, hi);
    }
    return;
  }

  if (blk < 368) {  // ---- scan + window diff ----
    int task = blk - 64;   // 0..303
    const float* ra;
    const float* rb = nullptr;
    float* outD;
    if (task < 16)      { ra = rel + (size_t)task * RELP; outD = d1q + (size_t)task * 256; }
    else if (task < 32) { ra = rel + (size_t)task * RELP; outD = d1k + (size_t)(task - 16) * 256; }
    else {
      int i = (task < 168) ? task - 32 : task - 168;
      int rem = i, d = 0;
      while (rem >= 16 - d) { rem -= 16 - d; ++d; }
      int d2 = d + rem;
      if (task < 168) {
        ra = rel + (size_t)d * RELP; rb = rel + (size_t)d2 * RELP;
        outD = d2q + (size_t)i * 256;
      } else {
        ra = rel + (size_t)(16 + d) * RELP; rb = rel + (size_t)(16 + d2) * RELP;
        outD = d2k + (size_t)i * 256;
      }
    }
    __shared__ float buf[256];
    __shared__ float pbuf[502];
    int t = tid;
    int i0 = 2 * t, i1 = 2 * t + 1;
    float a0 = (i0 < RELP) ? (rb ? ra[i0] * rb[i0] : ra[i0]) : 0.f;
    float a1 = (i1 < RELP) ? (rb ? ra[i1] * rb[i1] : ra[i1]) : 0.f;
    buf[t] = a0 + a1;
    __syncthreads();
#pragma unroll
    for (int off = 1; off < 256; off <<= 1) {
      float v = buf[t];
      float add = (t >= off) ? buf[t - off] : 0.f;
      __syncthreads();
      buf[t] = v + add;
      __syncthreads();
    }
    float ex = buf[t] - (a0 + a1);      // P[2t]
    if (i0 <= RELP) pbuf[i0] = ex;
    if (i1 <= RELP) pbuf[i1] = ex + a0; // P[2t+1]
    __syncthreads();
    if (t <= 250) outD[t] = pbuf[501 - t] - pbuf[250 - t];
    return;
  }

  // ---- GEMM ----
  int g = blk - 368;
  int l0 = (g & 3) * 64;
  int o0 = ((g >> 2) & 7) * 64;
  int bb = g >> 5;
  int b = bb / 15, hi = bb % 15;
  const float* src;
  const float* wmat;
  int orow0;
  if (o0 < 128)      { wmat = wk; orow0 = o0;       src = x; }
  else if (o0 < 256) { wmat = wq; orow0 = o0 - 128; src = y; }
  else               { wmat = wv; orow0 = o0 - 256; src = x; }

  __shared__ _Float16 Ah[64][68];   // [o][k]
  __shared__ _Float16 Bh[64][68];   // [k][l]

  int lane = tid & 63, wv4 = tid >> 6;
  int wo = wv4 >> 1, wl = wv4 & 1;
  int m = lane & 31, kh = lane >> 5;

  f32x16_t acc = {};

  int cA = tid & 63, ogA = tid >> 6;
  int lB = tid & 63, kgB = tid >> 6;
  int lglob = l0 + lB;
  bool lok = (lglob < WPOS);
  const float* xcol = src + (size_t)(((size_t)b * 256) * 15 + hi) * WPOS + lglob;

  for (int c0 = 0; c0 < 256; c0 += 64) {
#pragma unroll
    for (int i = 0; i < 16; ++i) {
      int o = ogA * 16 + i;
      Ah[o][cA] = (_Float16)wmat[(size_t)(orow0 + o) * 256 + c0 + cA];
    }
#pragma unroll
    for (int i = 0; i < 16; ++i) {
      int k = kgB * 16 + i;
      float v = lok ? xcol[(size_t)(c0 + k) * 15 * WPOS] : 0.f;
      Bh[k][lB] = (_Float16)v;
    }
    __syncthreads();
#pragma unroll
    for (int ks = 0; ks < 4; ++ks) {
      const _Float16* ap = &Ah[wo * 32 + m][ks * 16 + kh * 8];
      uint2 aLo = *(const uint2*)(ap);
      uint2 aHi = *(const uint2*)(ap + 4);
      uint4 au = {aLo.x, aLo.y, aHi.x, aHi.y};
      half8_t af = __builtin_bit_cast(half8_t, au);
      half8_t bf;
      int kb = ks * 16 + kh * 8;
      int bcol = wl * 32 + m;
#pragma unroll
      for (int e = 0; e < 8; ++e) bf[e] = Bh[kb + e][bcol];
      acc = __builtin_amdgcn_mfma_f32_32x32x16_f16(af, bf, acc, 0, 0, 0);
    }
    __syncthreads();
  }

  int n = lane & 31;
  int lout = l0 + wl * 32 + n;
  if (lout < WPOS) {
#pragma unroll
    for (int r = 0; r < 16; ++r) {
      int mrow = (r & 3) + 8 * (r >> 2) + 4 * kh;
      int o = o0 + wo * 32 + mrow;
      z[((size_t)bb * NCH + o) * WPOS + lout] = acc[r];
    }
  }

  // ---- channel partial sums: single writer per (part, o) -> no atomics ----
  int part = ((g & 3) * 2 + wl) * NBB + bb;
#pragma unroll
  for (int r = 0; r < 16; ++r) {
    float s = acc[r];
    float s2 = s * s;
#pragma unroll
    for (int m2 = 1; m2 < 32; m2 <<= 1) {
      s  += __shfl_xor(s, m2, 64);
      s2 += __shfl_xor(s2, m2, 64);
    }
    if (n == 0) {
      int mrow = (r & 3) + 8 * (r >> 2) + 4 * kh;
      int o = o0 + wo * 32 + mrow;
      cps[(size_t)part * 512 + o] = s;
      cps2[(size_t)part * 512 + o] = s2;
    }
  }
}

// ---------------- K1b: reduce 240 channel partials -> csum/csum2 ----------------
__global__ __launch_bounds__(256) void k_cred(
    const float* __restrict__ cps, const float* __restrict__ cps2,
    float* __restrict__ csum, float* __restrict__ csum2) {
  int c = blockIdx.x * 16 + (threadIdx.x & 15);
  int grp = threadIdx.x >> 4;           // 16 groups x 15 parts = 240
  __shared__ float r1[256], r2[256];
  float s = 0.f, s2 = 0.f;
  for (int i = 0; i < 15; ++i) {
    int p = grp * 15 + i;
    s += cps[(size_t)p * 512 + c];
    s2 += cps2[(size_t)p * 512 + c];
  }
  r1[threadIdx.x] = s; r2[threadIdx.x] = s2;
  __syncthreads();
  for (int st = 128; st >= 16; st >>= 1) {
    if (threadIdx.x < st) {
      r1[threadIdx.x] += r1[threadIdx.x + st];
      r2[threadIdx.x] += r2[threadIdx.x + st];
    }
    __syncthreads();
  }
  if (threadIdx.x < 16) {
    csum[c] = r1[threadIdx.x];
    csum2[c] = r2[threadIdx.x];
  }
}

// ---------------- helpers ----------------
__device__ __forceinline__ float block_reduce(float v, float* red, int tid) {
  red[tid] = v; __syncthreads();
  for (int s = 128; s > 0; s >>= 1) {
    if (tid < s) red[tid] += red[tid + s];
    __syncthreads();
  }
  float r = red[0]; __syncthreads();
  return r;
}

__device__ __forceinline__ void chan_affine(
    int ch, const float* gk, const float* bk, const float* gq, const float* bq,
    const float* gkq, const float* bkq, const float* csum, const float* csum2,
    float& a, float& bout) {
  float g, bi;
  if (ch < 128)      { g = gk[ch];        bi = bk[ch]; }
  else if (ch < 256) { g = gq[ch - 128];  bi = bq[ch - 128]; }
  else               { g = gkq[ch - 256]; bi = bkq[ch - 256]; }
  float n = (float)(NBB * WPOS);
  float mean = csum[ch] / n;
  float var = csum2[ch] / n - mean * mean;
  a = g / sqrtf(var + NEPS);
  bout = bi - mean * a;
}

// ---------------- K2: merged norm_vh (blocks 0..959) + lstats1 (960..1919) ----------------
__global__ __launch_bounds__(256) void k_mid(
    const float* __restrict__ z,
    const float* __restrict__ gk, const float* __restrict__ bk,
    const float* __restrict__ gq, const float* __restrict__ bq,
    const float* __restrict__ gkq, const float* __restrict__ bkq,
    const float* __restrict__ csum, const float* __restrict__ csum2,
    unsigned* __restrict__ vh,
    const float* __restrict__ d1q, const float* __restrict__ d1k,
    const float* __restrict__ d2q, const float* __restrict__ d2k,
    float* __restrict__ lpp) {
  int blk = blockIdx.x;
  bool isV = (blk < 960);
  int sblk = isV ? blk : blk - 960;
  int bbh = sblk % 240, sub = sblk / 240;
  int bb = bbh >> 3, h = bbh & 7;
  int tid = threadIdx.x;

  __shared__ __align__(16) float pool[16 * 68 * 2];
  __shared__ float red[256];
  __shared__ float caL[32], cbL[32];
  __shared__ int pairLUT[136];

  if (tid < 32) {
    int ch = h * 64 + (isV ? 32 + tid : tid);
    chan_affine(ch, gk, bk, gq, bq, gkq, bkq, csum, csum2, caL[tid], cbL[tid]);
  } else if (tid >= 64 && tid < 200) {
    int i = tid - 64, rem = i, d = 0;
    while (rem >= 16 - d) { rem -= 16 - d; ++d; }
    pairLUT[i] = (d << 4) | (d + rem);
  }
  __syncthreads();

  if (isV) {
    float (*T)[65] = (float(*)[65])pool;
    int l0 = sub * 64;
    const float* zv = z + ((size_t)bb * NCH + h * 64 + 32) * WPOS;
    for (int i = tid; i < 32 * 64; i += 256) {
      int ch = i >> 6, l = i & 63;
      int gl = l0 + l;
      T[ch][l] = (gl < WPOS) ? (caL[ch] * zv[(size_t)ch * WPOS + gl] + cbL[ch]) : 0.f;
    }
    __syncthreads();
    int p0 = l0 >> 1;
    for (int i = tid; i < 32 * 32; i += 256) {
      int pl = i >> 5, ch = i & 31;
      int gp = p0 + pl;
      if (gp < 128)
        vh[((size_t)bbh * 128 + gp) * 32 + ch] = packh2(T[ch][2 * pl], T[ch][2 * pl + 1]);
    }
    return;
  }

  float (*qs)[68] = (float(*)[68])pool;
  float (*ks)[68] = (float(*)[68])(pool + 16 * 68);
  int x0 = sub * 64;
  const float* zb = z + ((size_t)bb * NCH + h * 64) * WPOS;
  for (int idx = tid; idx < 16 * 64; idx += 256) {
    int d = idx >> 6, xl = idx & 63;
    int xg = x0 + xl;
    float kv = 0.f, qv = 0.f;
    if (xg < WPOS) {
      kv = caL[d] * zb[(size_t)d * WPOS + xg] + cbL[d];
      qv = caL[16 + d] * zb[(size_t)(16 + d) * WPOS + xg] + cbL[16 + d];
    }
    ks[d][xl] = kv; qs[d][xl] = qv;
  }
  __syncthreads();
  float* outp = lpp + ((size_t)bbh * 4 + sub) * 548;
  if (tid < 16) {
    float s = 0.f;
    for (int xl = 0; xl < 64; ++xl) s += qs[tid][xl];
    outp[516 + tid] = s;
  } else if (tid < 32) {
    float s = 0.f;
    for (int xl = 0; xl < 64; ++xl) s += ks[tid - 16][xl];
    outp[532 + (tid - 16)] = s;
  }
  {
    int d = tid >> 4, d2 = tid & 15;
    float g1 = 0.f, g2 = 0.f;
    for (int xl = 0; xl < 64; ++xl) {
      g1 += qs[d][xl] * qs[d2][xl];
      g2 += ks[d][xl] * ks[d2][xl];
    }
    outp[tid] = g1;
    outp[256 + tid] = g2;
  }
  // ---- band terms via precomputed window diffs (symmetric-halved) ----
  float v_sumqr = 0.f, v_sqqr = 0.f, v_sumkr = 0.f, v_sqkr = 0.f;
  {
    int xl = tid & 63, wv = tid >> 6;
    int xg = x0 + xl;
    if (xg < WPOS) {
      for (int i = wv; i < 136; i += 4) {
        int pc = pairLUT[i];
        int d = pc >> 4, d2 = pc & 15;
        float wgt = (d == d2) ? 1.f : 2.f;
        v_sqqr += wgt * qs[d][xl] * qs[d2][xl] * d2q[(size_t)i * 256 + xg];
        v_sqkr += wgt * ks[d][xl] * ks[d2][xl] * d2k[(size_t)i * 256 + xg];
      }
      for (int d = wv; d < 16; d += 4) {
        v_sumqr += qs[d][xl] * d1q[(size_t)d * 256 + xg];
        v_sumkr += ks[d][xl] * d1k[(size_t)d * 256 + xg];
      }
    }
  }
  float r1 = block_reduce(v_sumqr, red, tid);
  float r2 = block_reduce(v_sqqr, red, tid);
  float r3 = block_reduce(v_sumkr, red, tid);
  float r4 = block_reduce(v_sqkr, red, tid);
  if (tid == 0) { outp[512] = r1; outp[513] = r2; outp[514] = r3; outp[515] = r4; }
}

// ---------------- K3: combine partials -> lp[bbh][6] (plain writes) ----------------
__global__ __launch_bounds__(256) void k_lstats2(const float* __restrict__ lpp,
                                                 float* __restrict__ lp) {
  int bbh = blockIdx.x;
  int tid = threadIdx.x;
  __shared__ float red[256];
  __shared__ float qsums[16], ksums[16];
  const float* b0 = lpp + (size_t)bbh * 4 * 548;
  float qg = b0[tid] + b0[548 + tid] + b0[1096 + tid] + b0[1644 + tid];
  float kg = b0[256 + tid] + b0[804 + tid] + b0[1352 + tid] + b0[1900 + tid];
  if (tid < 16) {
    qsums[tid] = b0[516 + tid] + b0[1064 + tid] + b0[1612 + tid] + b0[2160 + tid];
    ksums[tid] = b0[532 + tid] + b0[1080 + tid] + b0[1628 + tid] + b0[2176 + tid];
  }
  float sqqk = block_reduce(qg * kg, red, tid);
  if (tid == 0) {
    float sum_qk = 0.f;
    for (int d = 0; d < 16; ++d) sum_qk += qsums[d] * ksums[d];
    float s1 = 0.f, s2 = 0.f, s3 = 0.f, s4 = 0.f;
    for (int c = 0; c < 4; ++c) {
      const float* bc = b0 + (size_t)c * 548;
      s1 += bc[512]; s2 += bc[513]; s3 += bc[514]; s4 += bc[515];
    }
    float* o = lp + (size_t)bbh * 6;
    o[0] = sum_qk; o[1] = sqqk;
    o[2] = s1; o[3] = s2; o[4] = s3; o[5] = s4;
  }
}

// ---------------- K4: fused logits + softmax + MFMA attention ----------------
__global__ __launch_bounds__(256) void k_attn(
    const float* __restrict__ z,
    const float* __restrict__ gk, const float* __restrict__ bk,
    const float* __restrict__ gq, const float* __restrict__ bq,
    const float* __restrict__ gkq, const float* __restrict__ bkq,
    const float* __restrict__ csum, const float* __restrict__ csum2,
    const unsigned* __restrict__ vh,
    const unsigned* __restrict__ retc, const unsigned* __restrict__ vetp,
    const float* __restrict__ lp, const float* __restrict__ glog,
    float* __restrict__ out) {
  int blk = blockIdx.x;
  int bbh = blk % 240, tile = blk / 240;
  int bb = bbh >> 3, h = bbh & 7;
  int b = bb / 15, hi = bb % 15;
  int x0 = tile * 32;
  int nr = min(32, WPOS - x0);
  int tid = threadIdx.x;
  int lane = tid & 63, wvid = tid >> 6;

  const float LOG2E = 1.4426950408889634f;

  __shared__ __align__(16) unsigned Su[32 * 132];     // fp16 S, 264 halfs/row
  __shared__ __align__(16) unsigned winU[282 * 18];   // rel rows; later Cred
  __shared__ __align__(16) unsigned uSh[256];
  __shared__ float affL[72];                          // ca[32] cb[32] lsums[6]
  _Float16* S = (_Float16*)Su;
  unsigned* qsP = uSh;
  float* sred = (float*)uSh;
  float* Cred = (float*)winU;

  int pwin0 = 251 - x0 - nr;
  int nwin = 250 + nr;

  // ---- inline channel affine + logit stat sums over bb ----
  if (tid < 32) {
    int ch = h * 64 + tid;
    chan_affine(ch, gk, bk, gq, bq, gkq, bkq, csum, csum2, affL[tid], affL[32 + tid]);
  } else if (tid >= 64 && tid < 70) {
    int grp = (tid - 64) >> 1, off = (tid - 64) & 1;
    float s = 0.f;
    for (int bb2 = 0; bb2 < NBB; ++bb2)
      s += lp[(size_t)(bb2 * 8 + h) * 6 + grp * 2 + off];
    affL[64 + (tid - 64)] = s;
  }
  __syncthreads();
  float la_qk, la_qr, la_kr;
  {
    float n = (float)NBB * (float)WPOS * (float)WPOS;
    float m0 = affL[64] / n, v0 = affL[65] / n - m0 * m0;
    float m1 = affL[66] / n, v1 = affL[67] / n - m1 * m1;
    float m2 = affL[68] / n, v2 = affL[69] / n - m2 * m2;
    la_qk = glog[0 * 8 + h] / sqrtf(v0 + NEPS) * LOG2E;
    la_qr = glog[1 * 8 + h] / sqrtf(v1 + NEPS) * LOG2E;
    la_kr = glog[2 * 8 + h] / sqrtf(v2 + NEPS) * LOG2E;
  }

  const float* zb = z + ((size_t)bb * NCH + h * 64) * WPOS;

  // ---- stage rel window into LDS ----
  for (int i = tid; i < nwin * 16; i += 256) {
    int r = i >> 4, j = i & 15;
    winU[r * 18 + j] = retc[(size_t)(pwin0 + r) * 16 + j];
  }

  // ---- stage q tile (affine from raw z, fp16-packed) ----
  {
    int xx = tid & 31, j = tid >> 5;
    int xcl = min(x0 + xx, WPOS - 1);
    float q0 = affL[16 + 2 * j] * zb[(size_t)(16 + 2 * j) * WPOS + xcl] + affL[48 + 2 * j];
    float q1 = affL[17 + 2 * j] * zb[(size_t)(17 + 2 * j) * WPOS + xcl] + affL[49 + 2 * j];
    qsP[xx * 8 + j] = packh2(q0, q1);
  }

  // ---- k row per lane (affine from raw z), fp16-packed ----
  int yy = wvid * 64 + lane;
  int yc = min(yy, WPOS - 1);
  bool yok = (yy < WPOS);
  half2_t khv[8];
#pragma unroll
  for (int d = 0; d < 8; ++d) {
    float k0 = affL[2 * d]     * zb[(size_t)(2 * d) * WPOS + yc] + affL[32 + 2 * d];
    float k1 = affL[2 * d + 1] * zb[(size_t)(2 * d + 1) * WPOS + yc] + affL[33 + 2 * d];
    khv[d] = __builtin_bit_cast(half2_t, packh2(k0, k1));
  }
  __syncthreads();

  // ---- fused S: qk + qr + kr, log2 domain; lanes on y, loop over x ----
  {
    int rowbase = yc + nr - 1;
    for (int xx = 0; xx < nr; ++xx) {
      const unsigned* wr = &winU[(size_t)(rowbase - xx) * 18];
      const unsigned* qp = &qsP[xx * 8];
      float dqk = 0.f, dqr = 0.f, dkr = 0.f;
#pragma unroll
      for (int j2 = 0; j2 < 4; ++j2) {
        uint2 ue = *(const uint2*)(wr + 2 * j2);
        uint2 uk = *(const uint2*)(wr + 8 + 2 * j2);
        uint2 uq = *(const uint2*)(qp + 2 * j2);
        half2_t qe0 = ash2(ue.x), qe1 = ash2(ue.y);
        half2_t ke0 = ash2(uk.x), ke1 = ash2(uk.y);
        half2_t q0  = ash2(uq.x), q1  = ash2(uq.y);
        half2_t k0 = khv[2 * j2], k1 = khv[2 * j2 + 1];
        dqk = FDOT2(q0, k0, dqk);  dqk = FDOT2(q1, k1, dqk);
        dqr = FDOT2(q0, qe0, dqr); dqr = FDOT2(q1, qe1, dqr);
        dkr = FDOT2(k0, ke0, dkr); dkr = FDOT2(k1, ke1, dkr);
      }
      float sval = la_qk * dqk + la_qr * dqr + la_kr * dkr;
      S[xx * 264 + yy] = yok ? (_Float16)sval : (_Float16)0.f;
    }
  }
  // ---- zero pad: cols 256..263; full rows nr..31 (tile 7) ----
  for (int i = tid; i < 32 * 8; i += 256)
    S[(i >> 3) * 264 + 256 + (i & 7)] = (_Float16)0.f;
  if (nr < 32) {
    int ntail = (32 - nr) * 264;
    for (int i = tid; i < ntail; i += 256) S[nr * 264 + i] = (_Float16)0.f;
  }
  __syncthreads();

  // ---- softmax over y; lanes on x, 8 slices; pair-wise fp16 ----
  int xx = lane & 31;
  int sl = wvid * 2 + (lane >> 5);
  int ylo = sl * 32;
  const unsigned* Srp = Su + xx * 132;
  {
    float m = -1e30f;
    if (sl < 7) {
#pragma unroll
      for (int pp = 0; pp < 16; ++pp) {
        half2_t hp = ash2(Srp[(ylo >> 1) + pp]);
        m = fmaxf(m, fmaxf((float)hp[0], (float)hp[1]));
      }
    } else {
#pragma unroll
      for (int pp = 0; pp < 13; ++pp) {
        half2_t hp = ash2(Srp[112 + pp]);
        m = fmaxf(m, fmaxf((float)hp[0], (float)hp[1]));
      }
      m = fmaxf(m, (float)S[xx * 264 + 250]);
    }
    sred[sl * 32 + xx] = m;
  }
  __syncthreads();
  float rowm = sred[0 * 32 + xx];
#pragma unroll
  for (int s = 1; s < 8; ++s) rowm = fmaxf(rowm, sred[s * 32 + xx]);
  __syncthreads();
  {
    float sacc = 0.f;
    unsigned* Swp = Su + xx * 132;
    if (sl < 7) {
#pragma unroll
      for (int pp = 0; pp < 16; ++pp) {
        half2_t hp = ash2(Swp[(ylo >> 1) + pp]);
        float e0 = exp2f((float)hp[0] - rowm);
        float e1 = exp2f((float)hp[1] - rowm);
        Swp[(ylo >> 1) + pp] = packh2(e0, e1);
        sacc += e0 + e1;
      }
    } else {
#pragma unroll
      for (int pp = 0; pp < 13; ++pp) {
        half2_t hp = ash2(Swp[112 + pp]);
        float e0 = exp2f((float)hp[0] - rowm);
        float e1 = exp2f((float)hp[1] - rowm);
        Swp[112 + pp] = packh2(e0, e1);
        sacc += e0 + e1;
      }
      float e = exp2f((float)S[xx * 264 + 250] - rowm);
      S[xx * 264 + 250] = (_Float16)e;
      sacc += e;
    }
    sred[sl * 32 + xx] = sacc;
  }
  __syncthreads();
  float denom = 0.f;
#pragma unroll
  for (int s = 0; s < 8; ++s) denom += sred[s * 32 + xx];

  // ---- MFMA PV: C[d][x]; K-split across 4 waves ----
  f32x16_t acc = {};
  int xcol = lane & 31;
  int khh = lane >> 5;
  const _Float16* Srow = S + xcol * 264;
  {
    const unsigned* vhb = vh + (size_t)bbh * 128 * 32 + xcol;
#pragma unroll
    for (int ks = 0; ks < 4; ++ks) {
      int y0 = 64 * wvid + 16 * ks + 8 * khh;
      int t0 = y0 >> 1;
      uint4 au = {vhb[(size_t)(t0 + 0) * 32], vhb[(size_t)(t0 + 1) * 32],
                  vhb[(size_t)(t0 + 2) * 32], vhb[(size_t)(t0 + 3) * 32]};
      half8_t af = __builtin_bit_cast(half8_t, au);
      half8_t bf = *(const half8_t*)(Srow + y0);
      acc = __builtin_amdgcn_mfma_f32_32x32x16_f16(af, bf, acc, 0, 0, 0);
    }
    const unsigned* vpb = vetp + xcol;
    int ybase = xcol + x0 - 250;
#pragma unroll
    for (int ks = 0; ks < 8; ++ks) {
      int p0 = 128 * wvid + 16 * ks + 8 * khh;
      int t0 = p0 >> 1;
      uint4 au = {vpb[(size_t)(t0 + 0) * 32], vpb[(size_t)(t0 + 1) * 32],
                  vpb[(size_t)(t0 + 2) * 32], vpb[(size_t)(t0 + 3) * 32]};
      half8_t af = __builtin_bit_cast(half8_t, au);
      half8_t bf;
#pragma unroll
      for (int e = 0; e < 8; ++e) {
        int yv = ybase + p0 + e;
        bf[e] = ((unsigned)yv < 264u) ? Srow[yv] : (_Float16)0.f;
      }
      acc = __builtin_amdgcn_mfma_f32_32x32x16_f16(af, bf, acc, 0, 0, 0);
    }
  }

  // ---- cross-wave C reduction via Cred (winU space), wave 0 stores ----
  if (wvid > 0) {
    float* cp = Cred + ((size_t)(wvid - 1) * 64 + lane) * 17;
#pragma unroll
    for (int r = 0; r < 16; ++r) cp[r] = acc[r];
  }
  __syncthreads();
  if (wvid == 0) {
#pragma unroll
    for (int w2 = 0; w2 < 3; ++w2) {
      const float* cp = Cred + ((size_t)w2 * 64 + lane) * 17;
#pragma unroll
      for (int r = 0; r < 16; ++r) acc[r] += cp[r];
    }
    if (xcol < nr) {
      float rinv = 1.0f / denom;
      int xg = x0 + xcol;
#pragma unroll
      for (int r = 0; r < 16; ++r) {
        int d = (r & 3) + 8 * (r >> 2) + 4 * khh;
        out[(((size_t)b * 256 + h * 32 + d) * 15 + hi) * WPOS + xg] = acc[r] * rinv;
      }
    }
  }
}

// ---------------- launch ----------------
extern "C" void kernel_launch(void* const* d_in, const int* in_sizes, int n_in,
                              void* d_out, int out_size, void* d_ws, size_t ws_size,
                              hipStream_t stream) {
  const float* x    = (const float*)d_in[0];
  const float* y    = (const float*)d_in[1];
  const float* wk   = (const float*)d_in[2];
  const float* wq   = (const float*)d_in[3];
  const float* wv   = (const float*)d_in[4];
  const float* gk   = (const float*)d_in[5];
  const float* bk   = (const float*)d_in[6];
  const float* gq   = (const float*)d_in[7];
  const float* bq   = (const float*)d_in[8];
  const float* gkq  = (const float*)d_in[9];
  const float* bkq  = (const float*)d_in[10];
  const float* glog = (const float*)d_in[11];
  const float* rel  = (const float*)d_in[13];
  float* out = (float*)d_out;
  float* ws  = (float*)d_ws;

  float* z      = ws + OFF_Z;
  unsigned* vh  = (unsigned*)(ws + OFF_VH);
  unsigned* retc= (unsigned*)(ws + OFF_RETC);
  unsigned* vetp= (unsigned*)(ws + OFF_VETP);
  float* d1q    = ws + OFF_D1Q;
  float* d1k    = ws + OFF_D1K;
  float* d2q    = ws + OFF_D2Q;
  float* d2k    = ws + OFF_D2K;
  float* lpp    = ws + OFF_LPP;
  float* cps    = ws + OFF_CPS;
  float* cps2   = ws + OFF_CPS2;
  float* csum   = ws + OFF_CS;
  float* csum2  = ws + OFF_CS2;
  float* lp     = ws + OFF_LPF;

  k_gemm_pre<<<1328, 256, 0, stream>>>(x, y, wk, wq, wv, rel, z, cps, cps2,
                                       retc, vetp, d1q, d1k, d2q, d2k);
  k_cred<<<32, 256, 0, stream>>>(cps, cps2, csum, csum2);
  k_mid<<<1920, 256, 0, stream>>>(z, gk, bk, gq, bq, gkq, bkq, csum, csum2,
                                  vh, d1q, d1k, d2q, d2k, lpp);
  k_lstats2<<<240, 256, 0, stream>>>(lpp, lp);
  k_attn<<<240 * 8, 256, 0, stream>>>(z, gk, bk, gq, bq, gkq, bkq, csum, csum2,
                                      vh, retc, vetp, lp, glog, out);
}

// Round 16
// 99.368 us; speedup vs baseline: 1.6090x; 1.0138x over previous
//
#include <hip/hip_runtime.h>
#include <hip/hip_bf16.h>
#include <cstdint>

#define WPOS 251
#define NBB  30
#define NCH  512
#define RELP 501
#define NEPS 1e-5f

typedef _Float16 half2_t __attribute__((ext_vector_type(2)));
typedef _Float16 half8_t __attribute__((ext_vector_type(8)));
typedef float f32x16_t __attribute__((ext_vector_type(16)));

#if defined(__has_builtin)
#if __has_builtin(__builtin_amdgcn_fdot2)
#define FDOT2(a, b, c) __builtin_amdgcn_fdot2((a), (b), (c), false)
#endif
#endif
#ifndef FDOT2
#define FDOT2(a, b, c) ((float)(a)[0] * (float)(b)[0] + (float)(a)[1] * (float)(b)[1] + (c))
#endif

// ---------------- workspace layout (in float slots) ----------------
static constexpr size_t SZ_Z     = (size_t)NBB * NCH * WPOS;
static constexpr size_t OFF_Z    = 0;
static constexpr size_t OFF_VH   = OFF_Z + SZ_Z;                   // uint[bbh][128][32] half2 v pairs
static constexpr size_t SZ_VH    = (size_t)NBB * 8 * 128 * 32;
static constexpr size_t OFF_RETC = OFF_VH + SZ_VH;                 // uint[501][16]: qe|keR fp16 pairs
static constexpr size_t OFF_VETP = OFF_RETC + (size_t)RELP * 16;   // uint[256][32] half2 p-pairs
static constexpr size_t OFF_D1Q  = OFF_VETP + (size_t)256 * 32;    // [16][256] window diffs
static constexpr size_t OFF_D1K  = OFF_D1Q + (size_t)16 * 256;
static constexpr size_t OFF_D2Q  = OFF_D1K + (size_t)16 * 256;     // [136][256]
static constexpr size_t OFF_D2K  = OFF_D2Q + (size_t)136 * 256;
static constexpr size_t OFF_LPP  = OFF_D2K + (size_t)136 * 256;    // [960][548] partials
static constexpr size_t OFF_CPS  = OFF_LPP + (size_t)960 * 548;    // [240][512] channel sum partials
static constexpr size_t OFF_CPS2 = OFF_CPS + (size_t)240 * 512;    // [240][512]
static constexpr size_t OFF_CS   = OFF_CPS2 + (size_t)240 * 512;   // csum[512]
static constexpr size_t OFF_CS2  = OFF_CS + 512;                   // csum2[512]
static constexpr size_t OFF_LPF  = OFF_CS2 + 512;                  // lp[240][6]

static __device__ __forceinline__ unsigned packh2(float a, float b) {
  half2_t t;
  t[0] = (_Float16)a;
  t[1] = (_Float16)b;
  return __builtin_bit_cast(unsigned, t);
}
static __device__ __forceinline__ half2_t ash2(unsigned u) {
  return __builtin_bit_cast(half2_t, u);
}

// ---------------- K1: fused {rel prep | scans+diffs | kqv MFMA GEMM} ----------------
__global__ __launch_bounds__(256) void k_gemm_pre(
    const float* __restrict__ x, const float* __restrict__ y,
    const float* __restrict__ wk, const float* __restrict__ wq,
    const float* __restrict__ wv, const float* __restrict__ rel,
    float* __restrict__ z, float* __restrict__ cps, float* __restrict__ cps2,
    unsigned* __restrict__ retc, unsigned* __restrict__ vetp,
    float* __restrict__ d1q, float* __restrict__ d1k,
    float* __restrict__ d2q, float* __restrict__ d2k) {
  int blk = blockIdx.x;
  int tid = threadIdx.x;

  if (blk < 64) {   // ---- rel prep ----
    int idx = blk * 256 + tid;
    if (idx < RELP * 16) {
      int p = idx >> 4, j = idx & 15;
      float lo, hi;
      if (j < 8) {
        lo = rel[(size_t)(2 * j) * RELP + p];
        hi = rel[(size_t)(2 * j + 1) * RELP + p];
      } else {
        int jj = j - 8;
        lo = rel[(size_t)(16 + 2 * jj) * RELP + (500 - p)];
        hi = rel[(size_t)(17 + 2 * jj) * RELP + (500 - p)];
      }
      retc[(size_t)p * 16 + j] = packh2(lo, hi);
    } else if (idx < RELP * 16 + 256 * 32) {
      int i2 = idx - RELP * 16;
      int t = i2 >> 5, ch = i2 & 31;
      float lo = (2 * t <= 500) ? rel[(size_t)(32 + ch) * RELP + 2 * t] : 0.f;
      float hi = (2 * t + 1 <= 500) ? rel[(size_t)(32 + ch) * RELP + 2 * t + 1] : 0.f;
      vetp[(size_t)t * 32 + ch] = packh2(lo, hi);
    }
    return;
  }

  if (blk < 368) {  // ---- scan + window diff ----
    int task = blk - 64;   // 0..303
    const float* ra;
    const float* rb = nullptr;
    float* outD;
    if (task < 16)      { ra = rel + (size_t)task * RELP; outD = d1q + (size_t)task * 256; }
    else if (task < 32) { ra = rel + (size_t)task * RELP; outD = d1k + (size_t)(task - 16) * 256; }
    else {
      int i = (task < 168) ? task - 32 : task - 168;
      int rem = i, d = 0;
      while (rem >= 16 - d) { rem -= 16 - d; ++d; }
      int d2 = d + rem;
      if (task < 168) {
        ra = rel + (size_t)d * RELP; rb = rel + (size_t)d2 * RELP;
        outD = d2q + (size_t)i * 256;
      } else {
        ra = rel + (size_t)(16 + d) * RELP; rb = rel + (size_t)(16 + d2) * RELP;
        outD = d2k + (size_t)i * 256;
      }
    }
    __shared__ float buf[256];
    __shared__ float pbuf[502];
    int t = tid;
    int i0 = 2 * t, i1 = 2 * t + 1;
    float a0 = (i0 < RELP) ? (rb ? ra[i0] * rb[i0] : ra[i0]) : 0.f;
    float a1 = (i1 < RELP) ? (rb ? ra[i1] * rb[i1] : ra[i1]) : 0.f;
    buf[t] = a0 + a1;
    __syncthreads();
#pragma unroll
    for (int off = 1; off < 256; off <<= 1) {
      float v = buf[t];
      float add = (t >= off) ? buf[t - off] : 0.f;
      __syncthreads();
      buf[t] = v + add;
      __syncthreads();
    }
    float ex = buf[t] - (a0 + a1);
    if (i0 <= RELP) pbuf[i0] = ex;
    if (i1 <= RELP) pbuf[i1] = ex + a0;
    __syncthreads();
    if (t <= 250) outD[t] = pbuf[501 - t] - pbuf[250 - t];
    return;
  }

  // ---- GEMM ----
  int g = blk - 368;
  int l0 = (g & 3) * 64;
  int o0 = ((g >> 2) & 7) * 64;
  int bb = g >> 5;
  int b = bb / 15, hi = bb % 15;
  const float* src;
  const float* wmat;
  int orow0;
  if (o0 < 128)      { wmat = wk; orow0 = o0;       src = x; }
  else if (o0 < 256) { wmat = wq; orow0 = o0 - 128; src = y; }
  else               { wmat = wv; orow0 = o0 - 256; src = x; }

  __shared__ _Float16 Ah[64][68];   // [o][k]
  __shared__ _Float16 Bh[64][68];   // [k][l]

  int lane = tid & 63, wv4 = tid >> 6;
  int wo = wv4 >> 1, wl = wv4 & 1;
  int m = lane & 31, kh = lane >> 5;

  f32x16_t acc = {};

  int cA = tid & 63, ogA = tid >> 6;
  int lB = tid & 63, kgB = tid >> 6;
  int lglob = l0 + lB;
  bool lok = (lglob < WPOS);
  const float* xcol = src + (size_t)(((size_t)b * 256) * 15 + hi) * WPOS + lglob;

  for (int c0 = 0; c0 < 256; c0 += 64) {
#pragma unroll
    for (int i = 0; i < 16; ++i) {
      int o = ogA * 16 + i;
      Ah[o][cA] = (_Float16)wmat[(size_t)(orow0 + o) * 256 + c0 + cA];
    }
#pragma unroll
    for (int i = 0; i < 16; ++i) {
      int k = kgB * 16 + i;
      float v = lok ? xcol[(size_t)(c0 + k) * 15 * WPOS] : 0.f;
      Bh[k][lB] = (_Float16)v;
    }
    __syncthreads();
#pragma unroll
    for (int ks = 0; ks < 4; ++ks) {
      const _Float16* ap = &Ah[wo * 32 + m][ks * 16 + kh * 8];
      uint2 aLo = *(const uint2*)(ap);
      uint2 aHi = *(const uint2*)(ap + 4);
      uint4 au = {aLo.x, aLo.y, aHi.x, aHi.y};
      half8_t af = __builtin_bit_cast(half8_t, au);
      half8_t bf;
      int kb = ks * 16 + kh * 8;
      int bcol = wl * 32 + m;
#pragma unroll
      for (int e = 0; e < 8; ++e) bf[e] = Bh[kb + e][bcol];
      acc = __builtin_amdgcn_mfma_f32_32x32x16_f16(af, bf, acc, 0, 0, 0);
    }
    __syncthreads();
  }

  int n = lane & 31;
  int lout = l0 + wl * 32 + n;
  if (lout < WPOS) {
#pragma unroll
    for (int r = 0; r < 16; ++r) {
      int mrow = (r & 3) + 8 * (r >> 2) + 4 * kh;
      int o = o0 + wo * 32 + mrow;
      z[((size_t)bb * NCH + o) * WPOS + lout] = acc[r];
    }
  }

  int part = ((g & 3) * 2 + wl) * NBB + bb;
#pragma unroll
  for (int r = 0; r < 16; ++r) {
    float s = acc[r];
    float s2 = s * s;
#pragma unroll
    for (int m2 = 1; m2 < 32; m2 <<= 1) {
      s  += __shfl_xor(s, m2, 64);
      s2 += __shfl_xor(s2, m2, 64);
    }
    if (n == 0) {
      int mrow = (r & 3) + 8 * (r >> 2) + 4 * kh;
      int o = o0 + wo * 32 + mrow;
      cps[(size_t)part * 512 + o] = s;
      cps2[(size_t)part * 512 + o] = s2;
    }
  }
}

// ---------------- K1b: reduce 240 channel partials -> csum/csum2 ----------------
__global__ __launch_bounds__(256) void k_cred(
    const float* __restrict__ cps, const float* __restrict__ cps2,
    float* __restrict__ csum, float* __restrict__ csum2) {
  int c = blockIdx.x * 16 + (threadIdx.x & 15);
  int grp = threadIdx.x >> 4;
  __shared__ float r1[256], r2[256];
  float s = 0.f, s2 = 0.f;
  for (int i = 0; i < 15; ++i) {
    int p = grp * 15 + i;
    s += cps[(size_t)p * 512 + c];
    s2 += cps2[(size_t)p * 512 + c];
  }
  r1[threadIdx.x] = s; r2[threadIdx.x] = s2;
  __syncthreads();
  for (int st = 128; st >= 16; st >>= 1) {
    if (threadIdx.x < st) {
      r1[threadIdx.x] += r1[threadIdx.x + st];
      r2[threadIdx.x] += r2[threadIdx.x + st];
    }
    __syncthreads();
  }
  if (threadIdx.x < 16) {
    csum[c] = r1[threadIdx.x];
    csum2[c] = r2[threadIdx.x];
  }
}

// ---------------- helpers ----------------
__device__ __forceinline__ float block_reduce(float v, float* red, int tid) {
  red[tid] = v; __syncthreads();
  for (int s = 128; s > 0; s >>= 1) {
    if (tid < s) red[tid] += red[tid + s];
    __syncthreads();
  }
  float r = red[0]; __syncthreads();
  return r;
}

__device__ __forceinline__ void chan_affine(
    int ch, const float* gk, const float* bk, const float* gq, const float* bq,
    const float* gkq, const float* bkq, const float* csum, const float* csum2,
    float& a, float& bout) {
  float g, bi;
  if (ch < 128)      { g = gk[ch];        bi = bk[ch]; }
  else if (ch < 256) { g = gq[ch - 128];  bi = bq[ch - 128]; }
  else               { g = gkq[ch - 256]; bi = bkq[ch - 256]; }
  float n = (float)(NBB * WPOS);
  float mean = csum[ch] / n;
  float var = csum2[ch] / n - mean * mean;
  a = g / sqrtf(var + NEPS);
  bout = bi - mean * a;
}

// ---------------- K2: merged norm_vh (blocks 0..959) + lstats1 (960..1919) ----------------
__global__ __launch_bounds__(256) void k_mid(
    const float* __restrict__ z,
    const float* __restrict__ gk, const float* __restrict__ bk,
    const float* __restrict__ gq, const float* __restrict__ bq,
    const float* __restrict__ gkq, const float* __restrict__ bkq,
    const float* __restrict__ csum, const float* __restrict__ csum2,
    unsigned* __restrict__ vh,
    const float* __restrict__ d1q, const float* __restrict__ d1k,
    const float* __restrict__ d2q, const float* __restrict__ d2k,
    float* __restrict__ lpp) {
  int blk = blockIdx.x;
  bool isV = (blk < 960);
  int sblk = isV ? blk : blk - 960;
  int bbh = sblk % 240, sub = sblk / 240;
  int bb = bbh >> 3, h = bbh & 7;
  int tid = threadIdx.x;

  __shared__ __align__(16) float pool[16 * 68 * 2];
  __shared__ float red[256];
  __shared__ float caL[32], cbL[32];
  __shared__ int pairLUT[136];

  if (tid < 32) {
    int ch = h * 64 + (isV ? 32 + tid : tid);
    chan_affine(ch, gk, bk, gq, bq, gkq, bkq, csum, csum2, caL[tid], cbL[tid]);
  } else if (tid >= 64 && tid < 200) {
    int i = tid - 64, rem = i, d = 0;
    while (rem >= 16 - d) { rem -= 16 - d; ++d; }
    pairLUT[i] = (d << 4) | (d + rem);
  }
  __syncthreads();

  if (isV) {
    float (*T)[65] = (float(*)[65])pool;
    int l0 = sub * 64;
    const float* zv = z + ((size_t)bb * NCH + h * 64 + 32) * WPOS;
    for (int i = tid; i < 32 * 64; i += 256) {
      int ch = i >> 6, l = i & 63;
      int gl = l0 + l;
      T[ch][l] = (gl < WPOS) ? (caL[ch] * zv[(size_t)ch * WPOS + gl] + cbL[ch]) : 0.f;
    }
    __syncthreads();
    int p0 = l0 >> 1;
    for (int i = tid; i < 32 * 32; i += 256) {
      int pl = i >> 5, ch = i & 31;
      int gp = p0 + pl;
      if (gp < 128)
        vh[((size_t)bbh * 128 + gp) * 32 + ch] = packh2(T[ch][2 * pl], T[ch][2 * pl + 1]);
    }
    return;
  }

  float (*qs)[68] = (float(*)[68])pool;
  float (*ks)[68] = (float(*)[68])(pool + 16 * 68);
  int x0 = sub * 64;
  const float* zb = z + ((size_t)bb * NCH + h * 64) * WPOS;
  for (int idx = tid; idx < 16 * 64; idx += 256) {
    int d = idx >> 6, xl = idx & 63;
    int xg = x0 + xl;
    float kv = 0.f, qv = 0.f;
    if (xg < WPOS) {
      kv = caL[d] * zb[(size_t)d * WPOS + xg] + cbL[d];
      qv = caL[16 + d] * zb[(size_t)(16 + d) * WPOS + xg] + cbL[16 + d];
    }
    ks[d][xl] = kv; qs[d][xl] = qv;
  }
  __syncthreads();
  float* outp = lpp + ((size_t)bbh * 4 + sub) * 548;
  if (tid < 16) {
    float s = 0.f;
    for (int xl = 0; xl < 64; ++xl) s += qs[tid][xl];
    outp[516 + tid] = s;
  } else if (tid < 32) {
    float s = 0.f;
    for (int xl = 0; xl < 64; ++xl) s += ks[tid - 16][xl];
    outp[532 + (tid - 16)] = s;
  }
  {
    int d = tid >> 4, d2 = tid & 15;
    float g1 = 0.f, g2 = 0.f;
    for (int xl = 0; xl < 64; ++xl) {
      g1 += qs[d][xl] * qs[d2][xl];
      g2 += ks[d][xl] * ks[d2][xl];
    }
    outp[tid] = g1;
    outp[256 + tid] = g2;
  }
  float v_sumqr = 0.f, v_sqqr = 0.f, v_sumkr = 0.f, v_sqkr = 0.f;
  {
    int xl = tid & 63, wv = tid >> 6;
    int xg = x0 + xl;
    if (xg < WPOS) {
      for (int i = wv; i < 136; i += 4) {
        int pc = pairLUT[i];
        int d = pc >> 4, d2 = pc & 15;
        float wgt = (d == d2) ? 1.f : 2.f;
        v_sqqr += wgt * qs[d][xl] * qs[d2][xl] * d2q[(size_t)i * 256 + xg];
        v_sqkr += wgt * ks[d][xl] * ks[d2][xl] * d2k[(size_t)i * 256 + xg];
      }
      for (int d = wv; d < 16; d += 4) {
        v_sumqr += qs[d][xl] * d1q[(size_t)d * 256 + xg];
        v_sumkr += ks[d][xl] * d1k[(size_t)d * 256 + xg];
      }
    }
  }
  float r1 = block_reduce(v_sumqr, red, tid);
  float r2 = block_reduce(v_sqqr, red, tid);
  float r3 = block_reduce(v_sumkr, red, tid);
  float r4 = block_reduce(v_sqkr, red, tid);
  if (tid == 0) { outp[512] = r1; outp[513] = r2; outp[514] = r3; outp[515] = r4; }
}

// ---------------- K3: combine partials -> lp[bbh][6] (plain writes) ----------------
__global__ __launch_bounds__(256) void k_lstats2(const float* __restrict__ lpp,
                                                 float* __restrict__ lp) {
  int bbh = blockIdx.x;
  int tid = threadIdx.x;
  __shared__ float red[256];
  __shared__ float qsums[16], ksums[16];
  const float* b0 = lpp + (size_t)bbh * 4 * 548;
  float qg = b0[tid] + b0[548 + tid] + b0[1096 + tid] + b0[1644 + tid];
  float kg = b0[256 + tid] + b0[804 + tid] + b0[1352 + tid] + b0[1900 + tid];
  if (tid < 16) {
    qsums[tid] = b0[516 + tid] + b0[1064 + tid] + b0[1612 + tid] + b0[2160 + tid];
    ksums[tid] = b0[532 + tid] + b0[1080 + tid] + b0[1628 + tid] + b0[2176 + tid];
  }
  float sqqk = block_reduce(qg * kg, red, tid);
  if (tid == 0) {
    float sum_qk = 0.f;
    for (int d = 0; d < 16; ++d) sum_qk += qsums[d] * ksums[d];
    float s1 = 0.f, s2 = 0.f, s3 = 0.f, s4 = 0.f;
    for (int c = 0; c < 4; ++c) {
      const float* bc = b0 + (size_t)c * 548;
      s1 += bc[512]; s2 += bc[513]; s3 += bc[514]; s4 += bc[515];
    }
    float* o = lp + (size_t)bbh * 6;
    o[0] = sum_qk; o[1] = sqqk;
    o[2] = s1; o[3] = s2; o[4] = s3; o[5] = s4;
  }
}

// ---------------- K4: fused logits + softmax + MFMA attention ----------------
// winU stride 20 uints (80B): rows 16B-aligned -> ds_read_b128 window reads;
// lane-stride 20 dwords x b128 covers all 32 banks per 8 lanes (conflict-free).
__global__ __launch_bounds__(256) void k_attn(
    const float* __restrict__ z,
    const float* __restrict__ gk, const float* __restrict__ bk,
    const float* __restrict__ gq, const float* __restrict__ bq,
    const float* __restrict__ gkq, const float* __restrict__ bkq,
    const float* __restrict__ csum, const float* __restrict__ csum2,
    const unsigned* __restrict__ vh,
    const unsigned* __restrict__ retc, const unsigned* __restrict__ vetp,
    const float* __restrict__ lp, const float* __restrict__ glog,
    float* __restrict__ out) {
  int blk = blockIdx.x;
  int bbh = blk % 240, tile = blk / 240;
  int bb = bbh >> 3, h = bbh & 7;
  int b = bb / 15, hi = bb % 15;
  int x0 = tile * 32;
  int nr = min(32, WPOS - x0);
  int tid = threadIdx.x;
  int lane = tid & 63, wvid = tid >> 6;

  const float LOG2E = 1.4426950408889634f;

  __shared__ __align__(16) unsigned Su[32 * 132];     // fp16 S, 264 halfs/row
  __shared__ __align__(16) unsigned winU[282 * 20];   // rel rows (stride 20); later Cred
  __shared__ __align__(16) unsigned uSh[256];
  __shared__ float affL[72];                          // ca[32] cb[32] lsums[6]
  _Float16* S = (_Float16*)Su;
  unsigned* qsP = uSh;
  float* sred = (float*)uSh;
  float* Cred = (float*)winU;

  int pwin0 = 251 - x0 - nr;
  int nwin = 250 + nr;

  // ---- inline channel affine + logit stat sums over bb ----
  if (tid < 32) {
    int ch = h * 64 + tid;
    chan_affine(ch, gk, bk, gq, bq, gkq, bkq, csum, csum2, affL[tid], affL[32 + tid]);
  } else if (tid >= 64 && tid < 70) {
    int grp = (tid - 64) >> 1, off = (tid - 64) & 1;
    float s = 0.f;
    for (int bb2 = 0; bb2 < NBB; ++bb2)
      s += lp[(size_t)(bb2 * 8 + h) * 6 + grp * 2 + off];
    affL[64 + (tid - 64)] = s;
  }
  __syncthreads();
  float la_qk, la_qr, la_kr;
  {
    float n = (float)NBB * (float)WPOS * (float)WPOS;
    float m0 = affL[64] / n, v0 = affL[65] / n - m0 * m0;
    float m1 = affL[66] / n, v1 = affL[67] / n - m1 * m1;
    float m2 = affL[68] / n, v2 = affL[69] / n - m2 * m2;
    la_qk = glog[0 * 8 + h] / sqrtf(v0 + NEPS) * LOG2E;
    la_qr = glog[1 * 8 + h] / sqrtf(v1 + NEPS) * LOG2E;
    la_kr = glog[2 * 8 + h] / sqrtf(v2 + NEPS) * LOG2E;
  }

  const float* zb = z + ((size_t)bb * NCH + h * 64) * WPOS;

  // ---- stage rel window into LDS (stride 20) ----
  for (int i = tid; i < nwin * 16; i += 256) {
    int r = i >> 4, j = i & 15;
    winU[r * 20 + j] = retc[(size_t)(pwin0 + r) * 16 + j];
  }

  // ---- stage q tile (affine from raw z, fp16-packed) ----
  {
    int xx = tid & 31, j = tid >> 5;
    int xcl = min(x0 + xx, WPOS - 1);
    float q0 = affL[16 + 2 * j] * zb[(size_t)(16 + 2 * j) * WPOS + xcl] + affL[48 + 2 * j];
    float q1 = affL[17 + 2 * j] * zb[(size_t)(17 + 2 * j) * WPOS + xcl] + affL[49 + 2 * j];
    qsP[xx * 8 + j] = packh2(q0, q1);
  }

  // ---- k row per lane (affine from raw z), fp16-packed ----
  int yy = wvid * 64 + lane;
  int yc = min(yy, WPOS - 1);
  bool yok = (yy < WPOS);
  half2_t khv[8];
#pragma unroll
  for (int d = 0; d < 8; ++d) {
    float k0 = affL[2 * d]     * zb[(size_t)(2 * d) * WPOS + yc] + affL[32 + 2 * d];
    float k1 = affL[2 * d + 1] * zb[(size_t)(2 * d + 1) * WPOS + yc] + affL[33 + 2 * d];
    khv[d] = __builtin_bit_cast(half2_t, packh2(k0, k1));
  }
  __syncthreads();

  // ---- fused S: qk + qr + kr, log2 domain; b128 LDS reads ----
  {
    int rowbase = yc + nr - 1;
    for (int xx = 0; xx < nr; ++xx) {
      const unsigned* wr = &winU[(size_t)(rowbase - xx) * 20];
      const unsigned* qp = &qsP[xx * 8];
      uint4 ueA = *(const uint4*)(wr);          // qe pairs j=0..3
      uint4 ueB = *(const uint4*)(wr + 4);      // qe pairs j=4..7
      uint4 ukA = *(const uint4*)(wr + 8);      // ke pairs j=0..3
      uint4 ukB = *(const uint4*)(wr + 12);     // ke pairs j=4..7
      uint4 uqA = *(const uint4*)(qp);          // q pairs j=0..3
      uint4 uqB = *(const uint4*)(qp + 4);      // q pairs j=4..7
      float dqk = 0.f, dqr = 0.f, dkr = 0.f;
      {
        half2_t q0 = ash2(uqA.x), q1 = ash2(uqA.y), q2 = ash2(uqA.z), q3 = ash2(uqA.w);
        half2_t k0 = khv[0], k1 = khv[1], k2 = khv[2], k3 = khv[3];
        dqk = FDOT2(q0, k0, dqk); dqk = FDOT2(q1, k1, dqk);
        dqk = FDOT2(q2, k2, dqk); dqk = FDOT2(q3, k3, dqk);
        dqr = FDOT2(q0, ash2(ueA.x), dqr); dqr = FDOT2(q1, ash2(ueA.y), dqr);
        dqr = FDOT2(q2, ash2(ueA.z), dqr); dqr = FDOT2(q3, ash2(ueA.w), dqr);
        dkr = FDOT2(k0, ash2(ukA.x), dkr); dkr = FDOT2(k1, ash2(ukA.y), dkr);
        dkr = FDOT2(k2, ash2(ukA.z), dkr); dkr = FDOT2(k3, ash2(ukA.w), dkr);
      }
      {
        half2_t q4 = ash2(uqB.x), q5 = ash2(uqB.y), q6 = ash2(uqB.z), q7 = ash2(uqB.w);
        half2_t k4 = khv[4], k5 = khv[5], k6 = khv[6], k7 = khv[7];
        dqk = FDOT2(q4, k4, dqk); dqk = FDOT2(q5, k5, dqk);
        dqk = FDOT2(q6, k6, dqk); dqk = FDOT2(q7, k7, dqk);
        dqr = FDOT2(q4, ash2(ueB.x), dqr); dqr = FDOT2(q5, ash2(ueB.y), dqr);
        dqr = FDOT2(q6, ash2(ueB.z), dqr); dqr = FDOT2(q7, ash2(ueB.w), dqr);
        dkr = FDOT2(k4, ash2(ukB.x), dkr); dkr = FDOT2(k5, ash2(ukB.y), dkr);
        dkr = FDOT2(k6, ash2(ukB.z), dkr); dkr = FDOT2(k7, ash2(ukB.w), dkr);
      }
      float sval = la_qk * dqk + la_qr * dqr + la_kr * dkr;
      S[xx * 264 + yy] = yok ? (_Float16)sval : (_Float16)0.f;
    }
  }
  // ---- zero pad: cols 256..263; full rows nr..31 (tile 7) ----
  for (int i = tid; i < 32 * 8; i += 256)
    S[(i >> 3) * 264 + 256 + (i & 7)] = (_Float16)0.f;
  if (nr < 32) {
    int ntail = (32 - nr) * 264;
    for (int i = tid; i < ntail; i += 256) S[nr * 264 + i] = (_Float16)0.f;
  }
  __syncthreads();

  // ---- softmax over y; lanes on x, 8 slices; pair-wise fp16 ----
  int xx = lane & 31;
  int sl = wvid * 2 + (lane >> 5);
  int ylo = sl * 32;
  const unsigned* Srp = Su + xx * 132;
  {
    float m = -1e30f;
    if (sl < 7) {
#pragma unroll
      for (int pp = 0; pp < 16; ++pp) {
        half2_t hp = ash2(Srp[(ylo >> 1) + pp]);
        m = fmaxf(m, fmaxf((float)hp[0], (float)hp[1]));
      }
    } else {
#pragma unroll
      for (int pp = 0; pp < 13; ++pp) {
        half2_t hp = ash2(Srp[112 + pp]);
        m = fmaxf(m, fmaxf((float)hp[0], (float)hp[1]));
      }
      m = fmaxf(m, (float)S[xx * 264 + 250]);
    }
    sred[sl * 32 + xx] = m;
  }
  __syncthreads();
  float rowm = sred[0 * 32 + xx];
#pragma unroll
  for (int s = 1; s < 8; ++s) rowm = fmaxf(rowm, sred[s * 32 + xx]);
  __syncthreads();
  {
    float sacc = 0.f;
    unsigned* Swp = Su + xx * 132;
    if (sl < 7) {
#pragma unroll
      for (int pp = 0; pp < 16; ++pp) {
        half2_t hp = ash2(Swp[(ylo >> 1) + pp]);
        float e0 = exp2f((float)hp[0] - rowm);
        float e1 = exp2f((float)hp[1] - rowm);
        Swp[(ylo >> 1) + pp] = packh2(e0, e1);
        sacc += e0 + e1;
      }
    } else {
#pragma unroll
      for (int pp = 0; pp < 13; ++pp) {
        half2_t hp = ash2(Swp[112 + pp]);
        float e0 = exp2f((float)hp[0] - rowm);
        float e1 = exp2f((float)hp[1] - rowm);
        Swp[112 + pp] = packh2(e0, e1);
        sacc += e0 + e1;
      }
      float e = exp2f((float)S[xx * 264 + 250] - rowm);
      S[xx * 264 + 250] = (_Float16)e;
      sacc += e;
    }
    sred[sl * 32 + xx] = sacc;
  }
  __syncthreads();
  float denom = 0.f;
#pragma unroll
  for (int s = 0; s < 8; ++s) denom += sred[s * 32 + xx];

  // ---- MFMA PV: C[d][x]; K-split across 4 waves ----
  f32x16_t acc = {};
  int xcol = lane & 31;
  int khh = lane >> 5;
  const _Float16* Srow = S + xcol * 264;
  {
    const unsigned* vhb = vh + (size_t)bbh * 128 * 32 + xcol;
#pragma unroll
    for (int ks = 0; ks < 4; ++ks) {
      int y0 = 64 * wvid + 16 * ks + 8 * khh;
      int t0 = y0 >> 1;
      uint4 au = {vhb[(size_t)(t0 + 0) * 32], vhb[(size_t)(t0 + 1) * 32],
                  vhb[(size_t)(t0 + 2) * 32], vhb[(size_t)(t0 + 3) * 32]};
      half8_t af = __builtin_bit_cast(half8_t, au);
      half8_t bf = *(const half8_t*)(Srow + y0);
      acc = __builtin_amdgcn_mfma_f32_32x32x16_f16(af, bf, acc, 0, 0, 0);
    }
    const unsigned* vpb = vetp + xcol;
    int ybase = xcol + x0 - 250;
#pragma unroll
    for (int ks = 0; ks < 8; ++ks) {
      int p0 = 128 * wvid + 16 * ks + 8 * khh;
      int t0 = p0 >> 1;
      uint4 au = {vpb[(size_t)(t0 + 0) * 32], vpb[(size_t)(t0 + 1) * 32],
                  vpb[(size_t)(t0 + 2) * 32], vpb[(size_t)(t0 + 3) * 32]};
      half8_t af = __builtin_bit_cast(half8_t, au);
      half8_t bf;
#pragma unroll
      for (int e = 0; e < 8; ++e) {
        int yv = ybase + p0 + e;
        bf[e] = ((unsigned)yv < 264u) ? Srow[yv] : (_Float16)0.f;
      }
      acc = __builtin_amdgcn_mfma_f32_32x32x16_f16(af, bf, acc, 0, 0, 0);
    }
  }

  // ---- cross-wave C reduction via Cred (winU space), wave 0 stores ----
  if (wvid > 0) {
    float* cp = Cred + ((size_t)(wvid - 1) * 64 + lane) * 17;
#pragma unroll
    for (int r = 0; r < 16; ++r) cp[r] = acc[r];
  }
  __syncthreads();
  if (wvid == 0) {
#pragma unroll
    for (int w2 = 0; w2 < 3; ++w2) {
      const float* cp = Cred + ((size_t)w2 * 64 + lane) * 17;
#pragma unroll
      for (int r = 0; r < 16; ++r) acc[r] += cp[r];
    }
    if (xcol < nr) {
      float rinv = 1.0f / denom;
      int xg = x0 + xcol;
#pragma unroll
      for (int r = 0; r < 16; ++r) {
        int d = (r & 3) + 8 * (r >> 2) + 4 * khh;
        out[(((size_t)b * 256 + h * 32 + d) * 15 + hi) * WPOS + xg] = acc[r] * rinv;
      }
    }
  }
}

// ---------------- launch ----------------
extern "C" void kernel_launch(void* const* d_in, const int* in_sizes, int n_in,
                              void* d_out, int out_size, void* d_ws, size_t ws_size,
                              hipStream_t stream) {
  const float* x    = (const float*)d_in[0];
  const float* y    = (const float*)d_in[1];
  const float* wk   = (const float*)d_in[2];
  const float* wq   = (const float*)d_in[3];
  const float* wv   = (const float*)d_in[4];
  const float* gk   = (const float*)d_in[5];
  const float* bk   = (const float*)d_in[6];
  const float* gq   = (const float*)d_in[7];
  const float* bq   = (const float*)d_in[8];
  const float* gkq  = (const float*)d_in[9];
  const float* bkq  = (const float*)d_in[10];
  const float* glog = (const float*)d_in[11];
  const float* rel  = (const float*)d_in[13];
  float* out = (float*)d_out;
  float* ws  = (float*)d_ws;

  float* z      = ws + OFF_Z;
  unsigned* vh  = (unsigned*)(ws + OFF_VH);
  unsigned* retc= (unsigned*)(ws + OFF_RETC);
  unsigned* vetp= (unsigned*)(ws + OFF_VETP);
  float* d1q    = ws + OFF_D1Q;
  float* d1k    = ws + OFF_D1K;
  float* d2q    = ws + OFF_D2Q;
  float* d2k    = ws + OFF_D2K;
  float* lpp    = ws + OFF_LPP;
  float* cps    = ws + OFF_CPS;
  float* cps2   = ws + OFF_CPS2;
  float* csum   = ws + OFF_CS;
  float* csum2  = ws + OFF_CS2;
  float* lp     = ws + OFF_LPF;

  k_gemm_pre<<<1328, 256, 0, stream>>>(x, y, wk, wq, wv, rel, z, cps, cps2,
                                       retc, vetp, d1q, d1k, d2q, d2k);
  k_cred<<<32, 256, 0, stream>>>(cps, cps2, csum, csum2);
  k_mid<<<1920, 256, 0, stream>>>(z, gk, bk, gq, bq, gkq, bkq, csum, csum2,
                                  vh, d1q, d1k, d2q, d2k, lpp);
  k_lstats2<<<240, 256, 0, stream>>>(lpp, lp);
  k_attn<<<240 * 8, 256, 0, stream>>>(z, gk, bk, gq, bq, gkq, bkq, csum, csum2,
                                      vh, retc, vetp, lp, glog, out);
}